// Round 18
// baseline (765.857 us; speedup 1.0000x reference)
//
#include <hip/hip_runtime.h>
#include <hip/hip_bf16.h>

typedef __hip_bfloat16 bf16;
typedef __attribute__((ext_vector_type(8))) short short8v;
typedef __attribute__((ext_vector_type(4))) float f32x4;

#define Bz   4
#define Sz   320
#define FNz  64
#define Dz   256
#define HIDz 1024
#define TOK  (Bz*Sz*FNz)     // 81920 tokens
#define NSEQ (Bz*FNz)        // 256 column sequences
#define NTRz 256
#define NTEz 64
#define TTR  (NSEQ*NTRz)     // 65536 train tokens
#define TTE  (NSEQ*NTEz)     // 16384 test tokens
#define CHD  40960           // stage-D chunk (tokens)
#define SCALE 0.17677669529663687f   // 1/sqrt(32)

// Map a "column-view" token rr (sequence-major) to its element offset in the
// row-layout (B,S,FN,D) tensor. Ls==0 -> plain contiguous rows of 256.
__device__ __forceinline__ size_t rowOff(int rr, int Ls, int s0){
  if (Ls == 0) return (size_t)rr * Dz;
  int n = rr / Ls;              // n = b*FN + f
  int s = rr - n * Ls + s0;
  return (((size_t)(n >> 6) * Sz + s) * FNz + (n & 63)) * Dz;
}

__device__ __forceinline__ void store4bf(bf16* p, float a, float b, float c, float d){
  bf16 t0=__float2bfloat16(a), t1=__float2bfloat16(b),
       t2=__float2bfloat16(c), t3=__float2bfloat16(d);
  ushort4 u;
  u.x=*(unsigned short*)&t0; u.y=*(unsigned short*)&t1;
  u.z=*(unsigned short*)&t2; u.w=*(unsigned short*)&t3;
  *(ushort4*)p = u;
}

__device__ __forceinline__ ushort4 pack4bf(float a, float b, float c, float d){
  bf16 t0=__float2bfloat16(a), t1=__float2bfloat16(b),
       t2=__float2bfloat16(c), t3=__float2bfloat16(d);
  ushort4 u;
  u.x=*(unsigned short*)&t0; u.y=*(unsigned short*)&t1;
  u.z=*(unsigned short*)&t2; u.w=*(unsigned short*)&t3;
  return u;
}

__device__ __forceinline__ void store2bf(bf16* p, float a, float b){
  bf16 t0=__float2bfloat16(a), t1=__float2bfloat16(b);
  ushort2 u;
  u.x=*(unsigned short*)&t0; u.y=*(unsigned short*)&t1;
  *(ushort2*)p = u;
}

// LN stats of an 8-float slice distributed over a 32-lane half-wave.
__device__ __forceinline__ void halfwave_ln(float4 v0, float4 v1,
                                            float& mean, float& rsd){
  float s = v0.x+v0.y+v0.z+v0.w + v1.x+v1.y+v1.z+v1.w;
  float q = v0.x*v0.x+v0.y*v0.y+v0.z*v0.z+v0.w*v0.w
          + v1.x*v1.x+v1.y*v1.y+v1.z*v1.z+v1.w*v1.w;
  #pragma unroll
  for (int d = 1; d < 32; d <<= 1){ s += __shfl_xor(s, d); q += __shfl_xor(q, d); }
  mean = s * (1.0f/Dz);
  rsd  = rsqrtf(q * (1.0f/Dz) - mean*mean + 1e-5f);
}

// ----------------- f32 -> bf16 weight conversion (all weights, one launch) --
struct CvtArgs { const float* src[24]; bf16* dst[24]; };
__global__ __launch_bounds__(256) void cvt_multi(CvtArgs args){
  int i = (blockIdx.x * 256 + threadIdx.x) * 4;
  const float* s = args.src[blockIdx.y];
  bf16*        d = args.dst[blockIdx.y];
  float4 v = *(const float4*)(s + i);
  store4bf(d + i, v.x, v.y, v.z, v.w);
}

// ----------------- fused LayerNorm -> contiguous bf16 rows (x only) --------
__global__ __launch_bounds__(256) void ln_kernel(const float* __restrict__ src,
    bf16* __restrict__ dst, const float* __restrict__ g, const float* __restrict__ b){
  int rr   = blockIdx.x * 4 + (threadIdx.x >> 6);
  int lane = threadIdx.x & 63;
  size_t off = (size_t)rr * Dz + (size_t)lane * 4;
  float4 v = *(const float4*)(src + off);
  float s = v.x + v.y + v.z + v.w;
  float q = v.x*v.x + v.y*v.y + v.z*v.z + v.w*v.w;
  #pragma unroll
  for (int d = 1; d < 64; d <<= 1){ s += __shfl_xor(s, d); q += __shfl_xor(q, d); }
  float m   = s * (1.0f/Dz);
  float rsd = rsqrtf(q * (1.0f/Dz) - m*m + 1e-5f);
  float4 gv = *(const float4*)(g + lane*4);
  float4 bv = *(const float4*)(b + lane*4);
  store4bf(dst + off,
           (v.x-m)*rsd*gv.x + bv.x, (v.y-m)*rsd*gv.y + bv.y,
           (v.z-m)*rsd*gv.z + bv.z, (v.w-m)*rsd*gv.w + bv.w);
}

// ----------------- MFMA bf16 GEMM, bf16-A, bf16 store (lean) ---------------
// BM=128, BN=256, BK=32, 8 waves.  1D grid + XCD swizzle.
__global__ __launch_bounds__(512) void mgemm_store(
    const bf16* __restrict__ A, const bf16* __restrict__ Wb,
    const float* __restrict__ bias, const float* __restrict__ biasB,
    const float* __restrict__ biasC, bf16* __restrict__ Cp,
    int N, int K, int ncols){
  __shared__ bf16 As[128][40];
  __shared__ bf16 Bs[256][40];
  const int tid  = threadIdx.x;
  const int lane = tid & 63;
  const int wave = tid >> 6;
  int L   = blockIdx.x;
  int cpx = gridDim.x >> 3;
  int W   = (L & 7) * cpx + (L >> 3);
  int rowb = W / ncols, colb = W - rowb * ncols;
  const int r0 = rowb * 128;
  const int n0 = colb * 256;
  const int srow = tid >> 2;
  const int scol = (tid & 3) * 8;
  const int bprow = (srow & 64) + (srow & 15)*4 + ((srow >> 4) & 3);
  const bf16* ap  = A  + (size_t)(r0 + srow) * K + scol;
  const bf16* bp0 = Wb + (size_t)(n0 + bprow) * K + scol;
  const bf16* bp1 = Wb + (size_t)(n0 + 128 + bprow) * K + scol;
  const int wr = wave >> 2, wc = wave & 3;
  const int fr = lane & 15;
  const int fk = (lane >> 4) * 8;
  f32x4 acc[4][4] = {};
  for (int k0 = 0; k0 < K; k0 += 32){
    uint4 av  = *(const uint4*)(ap  + k0);
    uint4 bv0 = *(const uint4*)(bp0 + k0);
    uint4 bv1 = *(const uint4*)(bp1 + k0);
    __syncthreads();
    *(uint4*)&As[srow][scol]       = av;
    *(uint4*)&Bs[srow][scol]       = bv0;
    *(uint4*)&Bs[128 + srow][scol] = bv1;
    __syncthreads();
    short8v af[4], bf[4];
    #pragma unroll
    for (int m = 0; m < 4; ++m)
      af[m] = *(const short8v*)&As[wr*64 + m*16 + fr][fk];
    #pragma unroll
    for (int n = 0; n < 4; ++n)
      bf[n] = *(const short8v*)&Bs[wc*64 + n*16 + fr][fk];
    #pragma unroll
    for (int m = 0; m < 4; ++m)
      #pragma unroll
      for (int n = 0; n < 4; ++n)
        acc[m][n] = __builtin_amdgcn_mfma_f32_16x16x32_bf16(af[m], bf[n], acc[m][n], 0, 0, 0);
  }
  const int er = (lane >> 4) * 4;
  const float* bp = bias;
  if (biasB != nullptr) bp = (colb == 0) ? bias : ((colb == 1) ? biasB : biasC);
  const int cl = wc*64 + fr*4;
  float bb0 = bp[cl], bb1 = bp[cl+1], bb2 = bp[cl+2], bb3 = bp[cl+3];
  const int cbase = n0 + cl;
  #pragma unroll
  for (int m = 0; m < 4; ++m){
    #pragma unroll
    for (int j = 0; j < 4; ++j){
      int r = r0 + wr*64 + m*16 + er + j;
      store4bf(&Cp[(size_t)r * N + cbase],
               acc[m][0][j] + bb0, acc[m][1][j] + bb1,
               acc[m][2][j] + bb2, acc[m][3][j] + bb3);
    }
  }
}

// ----------------- MFMA bf16 GEMM, f32-A with inline LN, bf16 store --------
// A rows are (optionally column-view) f32 rows of Y; per-row (mean,rsd) from
// S; LN affine (lnG, lnB) applied during staging.
__global__ __launch_bounds__(512) void mgemm_storeF(
    const float* __restrict__ Yf, const bf16* __restrict__ Wb,
    const float* __restrict__ bias, const float* __restrict__ biasB,
    const float* __restrict__ biasC, bf16* __restrict__ Cp,
    const float2* __restrict__ S,
    const float* __restrict__ lnG, const float* __restrict__ lnB,
    int N, int K, int ncols, int aLs, int aS0){
  __shared__ bf16 As[128][40];
  __shared__ bf16 Bs[256][40];
  const int tid  = threadIdx.x;
  const int lane = tid & 63;
  const int wave = tid >> 6;
  int L   = blockIdx.x;
  int cpx = gridDim.x >> 3;
  int W   = (L & 7) * cpx + (L >> 3);
  int rowb = W / ncols, colb = W - rowb * ncols;
  const int r0 = rowb * 128;
  const int n0 = colb * 256;
  const int srow = tid >> 2;
  const int scol = (tid & 3) * 8;
  const int bprow = (srow & 64) + (srow & 15)*4 + ((srow >> 4) & 3);
  const size_t aro = rowOff(r0 + srow, aLs, aS0);
  const float* apF = Yf + aro + scol;
  float2 st = S[aro >> 8];          // (mean, rsd) of this row
  const float mean = st.x, rsd = st.y;
  const bf16* bp0 = Wb + (size_t)(n0 + bprow) * K + scol;
  const bf16* bp1 = Wb + (size_t)(n0 + 128 + bprow) * K + scol;
  const int wr = wave >> 2, wc = wave & 3;
  const int fr = lane & 15;
  const int fk = (lane >> 4) * 8;
  f32x4 acc[4][4] = {};
  for (int k0 = 0; k0 < K; k0 += 32){
    float4 u0 = *(const float4*)(apF + k0);
    float4 u1 = *(const float4*)(apF + k0 + 4);
    float4 g0 = *(const float4*)(lnG + k0 + scol);
    float4 g1 = *(const float4*)(lnG + k0 + scol + 4);
    float4 h0 = *(const float4*)(lnB + k0 + scol);
    float4 h1 = *(const float4*)(lnB + k0 + scol + 4);
    ushort4 a0 = pack4bf((u0.x-mean)*rsd*g0.x + h0.x, (u0.y-mean)*rsd*g0.y + h0.y,
                         (u0.z-mean)*rsd*g0.z + h0.z, (u0.w-mean)*rsd*g0.w + h0.w);
    ushort4 a1 = pack4bf((u1.x-mean)*rsd*g1.x + h1.x, (u1.y-mean)*rsd*g1.y + h1.y,
                         (u1.z-mean)*rsd*g1.z + h1.z, (u1.w-mean)*rsd*g1.w + h1.w);
    uint4 bv0 = *(const uint4*)(bp0 + k0);
    uint4 bv1 = *(const uint4*)(bp1 + k0);
    __syncthreads();
    *(ushort4*)&As[srow][scol]     = a0;
    *(ushort4*)&As[srow][scol + 4] = a1;
    *(uint4*)&Bs[srow][scol]       = bv0;
    *(uint4*)&Bs[128 + srow][scol] = bv1;
    __syncthreads();
    short8v af[4], bf[4];
    #pragma unroll
    for (int m = 0; m < 4; ++m)
      af[m] = *(const short8v*)&As[wr*64 + m*16 + fr][fk];
    #pragma unroll
    for (int n = 0; n < 4; ++n)
      bf[n] = *(const short8v*)&Bs[wc*64 + n*16 + fr][fk];
    #pragma unroll
    for (int m = 0; m < 4; ++m)
      #pragma unroll
      for (int n = 0; n < 4; ++n)
        acc[m][n] = __builtin_amdgcn_mfma_f32_16x16x32_bf16(af[m], bf[n], acc[m][n], 0, 0, 0);
  }
  const int er = (lane >> 4) * 4;
  const float* bp = bias;
  if (biasB != nullptr) bp = (colb == 0) ? bias : ((colb == 1) ? biasB : biasC);
  const int cl = wc*64 + fr*4;
  float bb0 = bp[cl], bb1 = bp[cl+1], bb2 = bp[cl+2], bb3 = bp[cl+3];
  const int cbase = n0 + cl;
  #pragma unroll
  for (int m = 0; m < 4; ++m){
    #pragma unroll
    for (int j = 0; j < 4; ++j){
      int r = r0 + wr*64 + m*16 + er + j;
      store4bf(&Cp[(size_t)r * N + cbase],
               acc[m][0][j] + bb0, acc[m][1][j] + bb1,
               acc[m][2][j] + bb2, acc[m][3][j] + bb3);
    }
  }
}

// ----------------- MFMA bf16 GEMM, f32 residual + per-row LN stats ---------
// N=256, ncols=1.  C[rowOff]=resid[rowOff]+v; writes S[rowmajor]=(mean,rsd).
__global__ __launch_bounds__(512) void mgemm_residS(
    const bf16* __restrict__ A, const bf16* __restrict__ Wb,
    const float* __restrict__ bias, float* __restrict__ Cp,
    const float* __restrict__ resid, float2* __restrict__ S,
    int K, int cLs, int cS0){
  __shared__ __align__(16) char smemraw[30720];
  bf16 (*As)[40] = reinterpret_cast<bf16(*)[40]>(smemraw);
  bf16 (*Bs)[40] = reinterpret_cast<bf16(*)[40]>(smemraw + 10240);
  const int tid  = threadIdx.x;
  const int lane = tid & 63;
  const int wave = tid >> 6;
  int L   = blockIdx.x;
  int cpx = gridDim.x >> 3;
  const int r0 = ((L & 7) * cpx + (L >> 3)) * 128;
  const int srow = tid >> 2;
  const int scol = (tid & 3) * 8;
  const int bprow = (srow & 64) + (srow & 15)*4 + ((srow >> 4) & 3);
  const bf16* ap  = A  + (size_t)(r0 + srow) * K + scol;
  const bf16* bp0 = Wb + (size_t)(bprow) * K + scol;
  const bf16* bp1 = Wb + (size_t)(128 + bprow) * K + scol;
  const int wr = wave >> 2, wc = wave & 3;
  const int fr = lane & 15;
  const int fk = (lane >> 4) * 8;
  f32x4 acc[4][4] = {};
  for (int k0 = 0; k0 < K; k0 += 32){
    uint4 av  = *(const uint4*)(ap  + k0);
    uint4 bv0 = *(const uint4*)(bp0 + k0);
    uint4 bv1 = *(const uint4*)(bp1 + k0);
    __syncthreads();
    *(uint4*)&As[srow][scol]       = av;
    *(uint4*)&Bs[srow][scol]       = bv0;
    *(uint4*)&Bs[128 + srow][scol] = bv1;
    __syncthreads();
    short8v af[4], bf[4];
    #pragma unroll
    for (int m = 0; m < 4; ++m)
      af[m] = *(const short8v*)&As[wr*64 + m*16 + fr][fk];
    #pragma unroll
    for (int n = 0; n < 4; ++n)
      bf[n] = *(const short8v*)&Bs[wc*64 + n*16 + fr][fk];
    #pragma unroll
    for (int m = 0; m < 4; ++m)
      #pragma unroll
      for (int n = 0; n < 4; ++n)
        acc[m][n] = __builtin_amdgcn_mfma_f32_16x16x32_bf16(af[m], bf[n], acc[m][n], 0, 0, 0);
  }
  const int er = (lane >> 4) * 4;
  float* fsm = (float*)smemraw;       // 16 rows x 260 floats
  const int cb = wc*64 + fr*4;
  float bb0 = bias[cb], bb1 = bias[cb+1], bb2 = bias[cb+2], bb3 = bias[cb+3];
  #pragma unroll
  for (int m = 0; m < 4; ++m){
    #pragma unroll
    for (int wrs = 0; wrs < 2; ++wrs){
      __syncthreads();
      if (wr == wrs){
        #pragma unroll
        for (int j = 0; j < 4; ++j){
          float4 t;
          t.x = acc[m][0][j] + bb0; t.y = acc[m][1][j] + bb1;
          t.z = acc[m][2][j] + bb2; t.w = acc[m][3][j] + bb3;
          *(float4*)&fsm[(er + j)*260 + cb] = t;
        }
      }
      __syncthreads();
      int rrow = r0 + wrs*64 + m*16 + (tid >> 5);
      int c0 = (tid & 31) * 8;
      size_t ro = rowOff(rrow, cLs, cS0) + c0;
      const float* fs = fsm + (tid >> 5)*260 + c0;
      float4 v0 = *(const float4*)(fs);
      float4 v1 = *(const float4*)(fs + 4);
      float4 q0 = *(const float4*)(resid + ro);
      float4 q1 = *(const float4*)(resid + ro + 4);
      v0.x += q0.x; v0.y += q0.y; v0.z += q0.z; v0.w += q0.w;
      v1.x += q1.x; v1.y += q1.y; v1.z += q1.z; v1.w += q1.w;
      *(float4*)(Cp + ro)     = v0;
      *(float4*)(Cp + ro + 4) = v1;
      float mean, rsd;
      halfwave_ln(v0, v1, mean, rsd);
      if ((tid & 31) == 0) S[ro >> 8] = make_float2(mean, rsd);
    }
  }
}

// ----------------- fused dual GEMM, f32-A with inline LN -------------------
// Hb[r][c] = (LN(A).W1^T + b1) * silu(LN(A).Wg^T + bg), A = Y row-major f32.
__global__ __launch_bounds__(512) void mgemm_dualF(
    const float* __restrict__ Yf, const bf16* __restrict__ W1b,
    const bf16* __restrict__ Wgb, const float* __restrict__ b1,
    const float* __restrict__ bg, bf16* __restrict__ Hb,
    const float2* __restrict__ S,
    const float* __restrict__ lnG, const float* __restrict__ lnB, int K){
  __shared__ bf16 As[128][40];
  __shared__ bf16 B1s[128][40];
  __shared__ bf16 B2s[128][40];
  const int tid  = threadIdx.x;
  const int lane = tid & 63;
  const int wave = tid >> 6;
  int L   = blockIdx.x;
  int cpx = gridDim.x >> 3;
  int W   = (L & 7) * cpx + (L >> 3);
  int rowb = W >> 3, colb = W & 7;
  const int r0 = rowb * 128;
  const int n0 = colb * 128;
  const int srow = tid >> 2;
  const int scol = (tid & 3) * 8;
  const int bprow = (srow & ~31) + (srow & 15)*2 + ((srow >> 4) & 1);
  const float* apF = Yf + (size_t)(r0 + srow) * Dz + scol;
  float2 st = S[r0 + srow];
  const float mean = st.x, rsd = st.y;
  const bf16* p1 = W1b + (size_t)(n0 + bprow) * K + scol;
  const bf16* p2 = Wgb + (size_t)(n0 + bprow) * K + scol;
  const int wr = wave >> 2, wc = wave & 3;
  const int fr = lane & 15;
  const int fk = (lane >> 4) * 8;
  f32x4 acc1[4][2] = {};
  f32x4 acc2[4][2] = {};
  for (int k0 = 0; k0 < K; k0 += 32){
    float4 u0 = *(const float4*)(apF + k0);
    float4 u1 = *(const float4*)(apF + k0 + 4);
    float4 g0 = *(const float4*)(lnG + k0 + scol);
    float4 g1 = *(const float4*)(lnG + k0 + scol + 4);
    float4 h0 = *(const float4*)(lnB + k0 + scol);
    float4 h1 = *(const float4*)(lnB + k0 + scol + 4);
    ushort4 a0 = pack4bf((u0.x-mean)*rsd*g0.x + h0.x, (u0.y-mean)*rsd*g0.y + h0.y,
                         (u0.z-mean)*rsd*g0.z + h0.z, (u0.w-mean)*rsd*g0.w + h0.w);
    ushort4 a1 = pack4bf((u1.x-mean)*rsd*g1.x + h1.x, (u1.y-mean)*rsd*g1.y + h1.y,
                         (u1.z-mean)*rsd*g1.z + h1.z, (u1.w-mean)*rsd*g1.w + h1.w);
    uint4 v1 = *(const uint4*)(p1 + k0);
    uint4 v2 = *(const uint4*)(p2 + k0);
    __syncthreads();
    *(ushort4*)&As[srow][scol]     = a0;
    *(ushort4*)&As[srow][scol + 4] = a1;
    *(uint4*)&B1s[srow][scol] = v1;
    *(uint4*)&B2s[srow][scol] = v2;
    __syncthreads();
    short8v af[4], bf1[2], bf2[2];
    #pragma unroll
    for (int m = 0; m < 4; ++m)
      af[m] = *(const short8v*)&As[wr*64 + m*16 + fr][fk];
    #pragma unroll
    for (int n = 0; n < 2; ++n){
      bf1[n] = *(const short8v*)&B1s[wc*32 + n*16 + fr][fk];
      bf2[n] = *(const short8v*)&B2s[wc*32 + n*16 + fr][fk];
    }
    #pragma unroll
    for (int m = 0; m < 4; ++m)
      #pragma unroll
      for (int n = 0; n < 2; ++n){
        acc1[m][n] = __builtin_amdgcn_mfma_f32_16x16x32_bf16(af[m], bf1[n], acc1[m][n], 0, 0, 0);
        acc2[m][n] = __builtin_amdgcn_mfma_f32_16x16x32_bf16(af[m], bf2[n], acc2[m][n], 0, 0, 0);
      }
  }
  const int er = (lane >> 4) * 4;
  const int c = n0 + wc*32 + fr*2;
  const float b10 = b1[c], b11 = b1[c+1];
  const float bg0 = bg[c], bg1 = bg[c+1];
  #pragma unroll
  for (int m = 0; m < 4; ++m){
    #pragma unroll
    for (int j = 0; j < 4; ++j){
      int r = r0 + wr*64 + m*16 + er + j;
      float v0 = acc1[m][0][j] + b10;
      float g0 = acc2[m][0][j] + bg0;
      float v1 = acc1[m][1][j] + b11;
      float g1 = acc2[m][1][j] + bg1;
      float h0 = v0 * g0 / (1.0f + __expf(-g0));
      float h1 = v1 * g1 / (1.0f + __expf(-g1));
      store2bf(&Hb[(size_t)r * HIDz + c], h0, h1);
    }
  }
}

// ============== MFMA flash attention, train self-attn (L=256) ==============
__global__ __launch_bounds__(256) void attn_t_m(
    const bf16* __restrict__ Q, const bf16* __restrict__ K,
    const bf16* __restrict__ V, bf16* __restrict__ O, int ld){
  __shared__ bf16 Klds[64][40];
  __shared__ bf16 Vt[32][72];
  __shared__ bf16 Plds[4][64][72];
  const int n = blockIdx.x, h = blockIdx.y;
  const int tid = threadIdx.x, lane = tid & 63, w = tid >> 6;
  const size_t ibase = (size_t)n * 256 * ld + (size_t)h * 32;
  const size_t obase = (size_t)n * 256 * Dz + (size_t)h * 32;
  const int l15 = lane & 15, l4 = lane >> 4;
  short8v qf[4];
  #pragma unroll
  for (int m = 0; m < 4; ++m)
    qf[m] = *(const short8v*)(Q + ibase + (size_t)(w*64 + m*16 + l15) * ld + l4*8);
  f32x4 accO[4][2] = {};
  float mrowq[4], lrowq[4], sclq[4];
  #pragma unroll
  for (int m=0;m<4;++m){ mrowq[m] = -1e30f; lrowq[m] = 0.f; }
  const f32x4 zero = {};
  for (int kb = 0; kb < 4; ++kb){
    __syncthreads();
    {
      int r = tid >> 2, c8 = (tid & 3) * 8;
      *(uint4*)&Klds[r][c8] = *(const uint4*)(K + ibase + (size_t)(kb*64 + r) * ld + c8);
      uint4 vr = *(const uint4*)(V + ibase + (size_t)(kb*64 + r) * ld + c8);
      const bf16* vb = (const bf16*)&vr;
      #pragma unroll
      for (int i = 0; i < 8; ++i) Vt[c8 + i][r] = vb[i];
    }
    __syncthreads();
    short8v kf[4];
    #pragma unroll
    for (int nn = 0; nn < 4; ++nn)
      kf[nn] = *(const short8v*)&Klds[nn*16 + l15][l4*8];
    f32x4 s2[4][4];
    #pragma unroll
    for (int m = 0; m < 4; ++m)
      #pragma unroll
      for (int nn = 0; nn < 4; ++nn)
        s2[m][nn] = __builtin_amdgcn_mfma_f32_16x16x32_bf16(kf[nn], qf[m], zero, 0,0,0);
    #pragma unroll
    for (int m = 0; m < 4; ++m){
      float mx = fmaxf(fmaxf(s2[m][0][0], s2[m][0][1]), fmaxf(s2[m][0][2], s2[m][0][3]));
      #pragma unroll
      for (int nn = 1; nn < 4; ++nn)
        mx = fmaxf(mx, fmaxf(fmaxf(s2[m][nn][0], s2[m][nn][1]),
                             fmaxf(s2[m][nn][2], s2[m][nn][3])));
      mx = fmaxf(mx, __shfl_xor(mx, 16));
      mx = fmaxf(mx, __shfl_xor(mx, 32));
      float mnew = fmaxf(mrowq[m], mx);
      float scl = __expf((mrowq[m] - mnew) * SCALE);
      mrowq[m] = mnew; sclq[m] = scl;
      float ps = 0.f;
      #pragma unroll
      for (int nn = 0; nn < 4; ++nn)
        #pragma unroll
        for (int j = 0; j < 4; ++j){
          float p = __expf((s2[m][nn][j] - mnew) * SCALE);
          s2[m][nn][j] = p; ps += p;
        }
      ps += __shfl_xor(ps, 16);
      ps += __shfl_xor(ps, 32);
      lrowq[m] = lrowq[m] * scl + ps;
    }
    #pragma unroll
    for (int m = 0; m < 4; ++m)
      #pragma unroll
      for (int j = 0; j < 4; ++j){
        float so = __shfl(sclq[m], l4*4 + j);
        accO[m][0][j] *= so; accO[m][1][j] *= so;
      }
    #pragma unroll
    for (int m = 0; m < 4; ++m)
      #pragma unroll
      for (int nn = 0; nn < 4; ++nn)
        store4bf(&Plds[w][m*16 + l15][nn*16 + l4*4],
                 s2[m][nn][0], s2[m][nn][1], s2[m][nn][2], s2[m][nn][3]);
    #pragma unroll
    for (int m = 0; m < 4; ++m){
      #pragma unroll
      for (int kt = 0; kt < 2; ++kt){
        short8v pf = *(const short8v*)&Plds[w][m*16 + l15][kt*32 + l4*8];
        #pragma unroll
        for (int dt = 0; dt < 2; ++dt){
          short8v vf = *(const short8v*)&Vt[dt*16 + l15][kt*32 + l4*8];
          accO[m][dt] = __builtin_amdgcn_mfma_f32_16x16x32_bf16(pf, vf, accO[m][dt], 0,0,0);
        }
      }
    }
  }
  #pragma unroll
  for (int m = 0; m < 4; ++m){
    #pragma unroll
    for (int j = 0; j < 4; ++j){
      float inv = 1.0f / __shfl(lrowq[m], l4*4 + j);
      int row = w*64 + m*16 + l4*4 + j;
      #pragma unroll
      for (int dt = 0; dt < 2; ++dt)
        O[obase + (size_t)row * Dz + dt*16 + l15] = __float2bfloat16(accO[m][dt][j] * inv);
    }
  }
}

// ============== MFMA flash attention, wave-per-(row,head) ==================
template<int NKB, int MASK>
__global__ __launch_bounds__(256) void attn_w(
    const bf16* __restrict__ Q, const bf16* __restrict__ K,
    const bf16* __restrict__ V, const float* __restrict__ mask,
    bf16* __restrict__ O, int ldq, int ldkv){
  __shared__ bf16 Klds[4][64][40];
  __shared__ bf16 Vt[4][32][72];
  __shared__ bf16 Plds[4][64][72];
  const int r = blockIdx.x;
  const int tid = threadIdx.x, lane = tid & 63, w = tid >> 6;
  const int h = blockIdx.y * 4 + w;
  const int l15 = lane & 15, l4 = lane >> 4;
  const size_t qoff = (size_t)r * 64 * ldq + (size_t)h * 32;
  const size_t koff = (size_t)r * (NKB*64) * ldkv + (size_t)h * 32;
  const size_t ooff = (size_t)r * 64 * Dz + (size_t)h * 32;
  short8v qf[4];
  #pragma unroll
  for (int m = 0; m < 4; ++m)
    qf[m] = *(const short8v*)(Q + qoff + (size_t)(m*16 + l15) * ldq + l4*8);
  f32x4 accO[4][2] = {};
  float mrowq[4], lrowq[4], sclq[4];
  #pragma unroll
  for (int m=0;m<4;++m){ mrowq[m] = -1e30f; lrowq[m] = 0.f; }
  const f32x4 zero = {};
  for (int kb = 0; kb < NKB; ++kb){
    {
      const bf16* kp = K + koff + (size_t)(kb*64 + lane) * ldkv;
      const bf16* vp = V + koff + (size_t)(kb*64 + lane) * ldkv;
      uint4 k0 = *(const uint4*)(kp);      uint4 k1 = *(const uint4*)(kp + 8);
      uint4 k2 = *(const uint4*)(kp + 16); uint4 k3 = *(const uint4*)(kp + 24);
      *(uint4*)&Klds[w][lane][0]  = k0; *(uint4*)&Klds[w][lane][8]  = k1;
      *(uint4*)&Klds[w][lane][16] = k2; *(uint4*)&Klds[w][lane][24] = k3;
      uint4 v0 = *(const uint4*)(vp);      uint4 v1 = *(const uint4*)(vp + 8);
      uint4 v2 = *(const uint4*)(vp + 16); uint4 v3 = *(const uint4*)(vp + 24);
      const bf16* vb0=(const bf16*)&v0; const bf16* vb1=(const bf16*)&v1;
      const bf16* vb2=(const bf16*)&v2; const bf16* vb3=(const bf16*)&v3;
      #pragma unroll
      for (int i = 0; i < 8; ++i){
        Vt[w][i][lane]      = vb0[i];
        Vt[w][8 + i][lane]  = vb1[i];
        Vt[w][16 + i][lane] = vb2[i];
        Vt[w][24 + i][lane] = vb3[i];
      }
    }
    short8v kf[4];
    #pragma unroll
    for (int nn = 0; nn < 4; ++nn)
      kf[nn] = *(const short8v*)&Klds[w][nn*16 + l15][l4*8];
    f32x4 s2[4][4];
    #pragma unroll
    for (int m = 0; m < 4; ++m)
      #pragma unroll
      for (int nn = 0; nn < 4; ++nn)
        s2[m][nn] = __builtin_amdgcn_mfma_f32_16x16x32_bf16(kf[nn], qf[m], zero, 0,0,0);
    if (MASK && h < 4){
      #pragma unroll
      for (int m = 0; m < 4; ++m)
        #pragma unroll
        for (int nn = 0; nn < 4; ++nn)
          #pragma unroll
          for (int j = 0; j < 4; ++j){
            int qq = m*16 + l15, kk = nn*16 + l4*4 + j;
            s2[m][nn][j] += (mask[qq*64 + kk] == 1.0f ? 0.0f : -1e30f);
          }
    }
    #pragma unroll
    for (int m = 0; m < 4; ++m){
      float mx = fmaxf(fmaxf(s2[m][0][0], s2[m][0][1]), fmaxf(s2[m][0][2], s2[m][0][3]));
      #pragma unroll
      for (int nn = 1; nn < 4; ++nn)
        mx = fmaxf(mx, fmaxf(fmaxf(s2[m][nn][0], s2[m][nn][1]),
                             fmaxf(s2[m][nn][2], s2[m][nn][3])));
      mx = fmaxf(mx, __shfl_xor(mx, 16));
      mx = fmaxf(mx, __shfl_xor(mx, 32));
      float mnew = fmaxf(mrowq[m], mx);
      float scl = __expf((mrowq[m] - mnew) * SCALE);
      mrowq[m] = mnew; sclq[m] = scl;
      float ps = 0.f;
      #pragma unroll
      for (int nn = 0; nn < 4; ++nn)
        #pragma unroll
        for (int j = 0; j < 4; ++j){
          float p = __expf((s2[m][nn][j] - mnew) * SCALE);
          s2[m][nn][j] = p; ps += p;
        }
      ps += __shfl_xor(ps, 16);
      ps += __shfl_xor(ps, 32);
      lrowq[m] = lrowq[m] * scl + ps;
    }
    #pragma unroll
    for (int m = 0; m < 4; ++m)
      #pragma unroll
      for (int j = 0; j < 4; ++j){
        float so = __shfl(sclq[m], l4*4 + j);
        accO[m][0][j] *= so; accO[m][1][j] *= so;
      }
    #pragma unroll
    for (int m = 0; m < 4; ++m)
      #pragma unroll
      for (int nn = 0; nn < 4; ++nn)
        store4bf(&Plds[w][m*16 + l15][nn*16 + l4*4],
                 s2[m][nn][0], s2[m][nn][1], s2[m][nn][2], s2[m][nn][3]);
    #pragma unroll
    for (int m = 0; m < 4; ++m){
      #pragma unroll
      for (int kt = 0; kt < 2; ++kt){
        short8v pf = *(const short8v*)&Plds[w][m*16 + l15][kt*32 + l4*8];
        #pragma unroll
        for (int dt = 0; dt < 2; ++dt){
          short8v vf = *(const short8v*)&Vt[w][dt*16 + l15][kt*32 + l4*8];
          accO[m][dt] = __builtin_amdgcn_mfma_f32_16x16x32_bf16(pf, vf, accO[m][dt], 0,0,0);
        }
      }
    }
  }
  #pragma unroll
  for (int m = 0; m < 4; ++m){
    #pragma unroll
    for (int j = 0; j < 4; ++j){
      float inv = 1.0f / __shfl(lrowq[m], l4*4 + j);
      int row = m*16 + l4*4 + j;
      #pragma unroll
      for (int dt = 0; dt < 2; ++dt)
        O[ooff + (size_t)row * Dz + dt*16 + l15] = __float2bfloat16(accO[m][dt][j] * inv);
    }
  }
}

// ---------------------------------------------------------------------------
extern "C" void kernel_launch(void* const* d_in, const int* in_sizes, int n_in,
                              void* d_out, int out_size, void* d_ws, size_t ws_size,
                              hipStream_t stream){
  (void)in_sizes; (void)n_in; (void)out_size; (void)ws_size;
  const float* x    = (const float*)d_in[0];
  const float* mask = (const float*)d_in[1];
  const float *Wqf=(const float*)d_in[2],  *Wkf=(const float*)d_in[3],
              *Wvf=(const float*)d_in[4],  *Wof=(const float*)d_in[5],
              *bqf=(const float*)d_in[6],  *bkf=(const float*)d_in[7],
              *bvf=(const float*)d_in[8],  *bof=(const float*)d_in[9],
              *gf =(const float*)d_in[10], *b2f=(const float*)d_in[11];
  const float *Wqt=(const float*)d_in[12], *Wkt=(const float*)d_in[13],
              *Wvt=(const float*)d_in[14], *Wot=(const float*)d_in[15],
              *bqt=(const float*)d_in[16], *bkt=(const float*)d_in[17],
              *bvt=(const float*)d_in[18], *bot=(const float*)d_in[19],
              *gt =(const float*)d_in[20], *b2t=(const float*)d_in[21];
  const float *Wqe=(const float*)d_in[22], *Wke=(const float*)d_in[23],
              *Wve=(const float*)d_in[24], *Woe=(const float*)d_in[25],
              *bqe=(const float*)d_in[26], *bke=(const float*)d_in[27],
              *bve=(const float*)d_in[28], *boe=(const float*)d_in[29],
              *ge =(const float*)d_in[30], *b2e=(const float*)d_in[31];
  const float *W1=(const float*)d_in[32], *b1=(const float*)d_in[33],
              *Wg=(const float*)d_in[34], *bg=(const float*)d_in[35],
              *W2=(const float*)d_in[36], *b2v=(const float*)d_in[37],
              *gm=(const float*)d_in[38], *bm=(const float*)d_in[39];

  float* Y = (float*)d_out;     // running activation in row layout (B,S,FN,D)

  char* wsb = (char*)d_ws;
  size_t off = 0;
  auto carve = [&](size_t bytes)->void*{
    void* p = wsb + off; off += (bytes + 255) & ~(size_t)255; return p;
  };
  bf16* Xn   = (bf16*)carve((size_t)TOK * Dz * 2);   // gf-LN of x (stage A input)
  bf16* QKVb = (bf16*)carve((size_t)TOK * 768 * 2);  // fused QKV
  bf16* Ob   = (bf16*)carve((size_t)TOK * Dz * 2);   // attention output
  bf16* Hb   = (bf16*)carve((size_t)CHD * HIDz * 2); // MLP fused-gate scratch
  bf16* WQKVf = (bf16*)carve((size_t)768*256*2);
  bf16* WQKVt = (bf16*)carve((size_t)768*256*2);
  bf16* WKVe  = (bf16*)carve((size_t)512*256*2);
  bf16* Wqeb  = (bf16*)carve((size_t)256*256*2);
  bf16* Wofb  = (bf16*)carve((size_t)256*256*2);
  bf16* Wotb  = (bf16*)carve((size_t)256*256*2);
  bf16* Woeb  = (bf16*)carve((size_t)256*256*2);
  bf16* W1b   = (bf16*)carve((size_t)HIDz*256*2);
  bf16* Wgb   = (bf16*)carve((size_t)HIDz*256*2);
  bf16* W2b   = (bf16*)carve((size_t)256*HIDz*2);

  // Per-row LN stats (mean,rsd), indexed by ROW-MAJOR token id.  Aliased into
  // QKVb's tail: stats live range starts AFTER stage-A attention consumed
  // QKVb; stage-B QKV writes only [0, TTR*768) = 50.3M elems and stage-C only
  // [0, 37.8M); stats sit at 62.59M..62.91M elems.  (TOK float2 = 0.66 MB)
  float2* S = (float2*)(QKVb + ((size_t)TOK * 768 - (size_t)TOK * 4));
  bf16* Qeb = QKVb + (size_t)TTR * 512;

  const int DD = Dz*Dz;   // 65536
  {
    CvtArgs ca;
    const float* s12[12] = {Wqf,Wkf,Wvf, Wqt,Wkt,Wvt, Wke,Wve, Wqe,Wof,Wot,Woe};
    bf16* d12[12] = {WQKVf,WQKVf+DD,WQKVf+2*DD, WQKVt,WQKVt+DD,WQKVt+2*DD,
                     WKVe,WKVe+DD, Wqeb,Wofb,Wotb,Woeb};
    for (int i = 0; i < 12; ++i){ ca.src[i] = s12[i]; ca.dst[i] = d12[i]; }
    const float* sh[3] = {W1, Wg, W2};
    bf16* dh[3] = {W1b, Wgb, W2b};
    for (int j = 0; j < 3; ++j)
      for (int p = 0; p < 4; ++p){
        ca.src[12 + j*4 + p] = sh[j] + (size_t)p * DD;
        ca.dst[12 + j*4 + p] = dh[j] + (size_t)p * DD;
      }
    cvt_multi<<<dim3(DD/1024, 24), 256, 0, stream>>>(ca);
  }

  // ---------------- Stage A: feature attention ----------------
  ln_kernel<<<TOK/4, 256, 0, stream>>>(x, Xn, gf, b2f);
  mgemm_store<<<3*(TOK/128), 512, 0, stream>>>(Xn, WQKVf, bqf, bkf, bvf, QKVb,
      768, 256, 3);
  attn_w<1,1><<<dim3(Bz*Sz, 2), 256, 0, stream>>>(QKVb, QKVb+256, QKVb+512, mask, Ob, 768, 768);
  // Wo + residual -> Y; per-row stats S1 (all TOK rows)
  mgemm_residS<<<TOK/128, 512, 0, stream>>>(Ob, Wofb, bof, Y, x, S, 256, 0, 0);

  // ---------------- Stage B: train self-attention ----------------
  // QKVt GEMM reads Y (train colview, f32) with gt-LN inline
  mgemm_storeF<<<3*(TTR/128), 512, 0, stream>>>(Y, WQKVt, bqt, bkt, bvt, QKVb,
      S, gt, b2t, 768, 256, 3, NTRz, 0);
  attn_t_m<<<dim3(NSEQ, 8), 256, 0, stream>>>(QKVb, QKVb+256, QKVb+512, Ob, 768);
  // Wot + residual -> Y train rows; stats S2 (train rows)
  mgemm_residS<<<TTR/128, 512, 0, stream>>>(Ob, Wotb, bot, Y, Y, S, 256, NTRz, 0);

  // ---------------- Stage C: cross attention ----------------
  // Qe reads Y test rows (stats still S1) with ge-LN; KVe reads Y train rows
  // (stats S2) with ge-LN.
  mgemm_storeF<<<TTE/128, 512, 0, stream>>>(Y, Wqeb, bqe, nullptr, nullptr, Qeb,
      S, ge, b2e, 256, 256, 1, NTEz, NTRz);
  mgemm_storeF<<<2*(TTR/128), 512, 0, stream>>>(Y, WKVe, bke, bve, bve, QKVb,
      S, ge, b2e, 512, 256, 2, NTRz, 0);
  attn_w<4,0><<<dim3(NSEQ, 2), 256, 0, stream>>>(Qeb, QKVb, QKVb+256,
      nullptr, Ob, 256, 512);
  // Woe + residual -> Y test rows; stats S3 (test rows)
  mgemm_residS<<<TTE/128, 512, 0, stream>>>(Ob, Woeb, boe, Y, Y, S, 256, NTEz, NTRz);

  // ---------------- Stage D: gated MLP (LN inline in dual A-loader) --------
  for (int c = 0; c < TOK/CHD; ++c){
    const float* Yc = Y + (size_t)c * CHD * Dz;
    mgemm_dualF<<<8*(CHD/128), 512, 0, stream>>>(Yc, W1b, Wgb, b1, bg,
        Hb, S + (size_t)c * CHD, gm, bm, 256);
    mgemm_residS<<<CHD/128, 512, 0, stream>>>(Hb, W2b, b2v, (float*)Yc, Yc, S,
        HIDz, 0, 0);
  }
}

// Round 19
// 720.409 us; speedup vs baseline: 1.0631x; 1.0631x over previous
//
#include <hip/hip_runtime.h>
#include <hip/hip_bf16.h>

typedef __hip_bfloat16 bf16;
typedef __attribute__((ext_vector_type(8))) short short8v;
typedef __attribute__((ext_vector_type(4))) float f32x4;

#define Bz   4
#define Sz   320
#define FNz  64
#define Dz   256
#define HIDz 1024
#define TOK  (Bz*Sz*FNz)     // 81920 tokens
#define NSEQ (Bz*FNz)        // 256 column sequences
#define NTRz 256
#define NTEz 64
#define TTR  (NSEQ*NTRz)     // 65536 train tokens
#define TTE  (NSEQ*NTEz)     // 16384 test tokens
#define CHD  40960           // stage-D chunk (tokens)
#define SCALE 0.17677669529663687f   // 1/sqrt(32)

// Map a "column-view" token rr (sequence-major) to its element offset in the
// row-layout (B,S,FN,D) tensor. Ls==0 -> plain contiguous rows of 256.
__device__ __forceinline__ size_t rowOff(int rr, int Ls, int s0){
  if (Ls == 0) return (size_t)rr * Dz;
  int n = rr / Ls;              // n = b*FN + f
  int s = rr - n * Ls + s0;
  return (((size_t)(n >> 6) * Sz + s) * FNz + (n & 63)) * Dz;
}

__device__ __forceinline__ void store4bf(bf16* p, float a, float b, float c, float d){
  bf16 t0=__float2bfloat16(a), t1=__float2bfloat16(b),
       t2=__float2bfloat16(c), t3=__float2bfloat16(d);
  ushort4 u;
  u.x=*(unsigned short*)&t0; u.y=*(unsigned short*)&t1;
  u.z=*(unsigned short*)&t2; u.w=*(unsigned short*)&t3;
  *(ushort4*)p = u;
}

__device__ __forceinline__ void store2bf(bf16* p, float a, float b){
  bf16 t0=__float2bfloat16(a), t1=__float2bfloat16(b);
  ushort2 u;
  u.x=*(unsigned short*)&t0; u.y=*(unsigned short*)&t1;
  *(ushort2*)p = u;
}

// XCD-aware swizzle: dispatch L -> work W; each XCD (L&7) owns a contiguous
// row-major work chunk, so col-blocks sharing an A-tile are time-adjacent on
// the SAME XCD (A-tile L2-resident).  nwg % 8 == 0 required.
__device__ __forceinline__ void xcd_work(int ncols, int& row, int& col){
  int L   = blockIdx.x;
  int cpx = gridDim.x >> 3;
  int W   = (L & 7) * cpx + (L >> 3);
  row = W / ncols;
  col = W - row * ncols;
}

// ----------------- f32 -> bf16 weight conversion (all weights, one launch) --
struct CvtArgs { const float* src[24]; bf16* dst[24]; };
__global__ __launch_bounds__(256) void cvt_multi(CvtArgs args){
  int i = (blockIdx.x * 256 + threadIdx.x) * 4;
  const float* s = args.src[blockIdx.y];
  bf16*        d = args.dst[blockIdx.y];
  float4 v = *(const float4*)(s + i);
  store4bf(d + i, v.x, v.y, v.z, v.w);
}

// ----------------- fused LayerNorm -> contiguous bf16 rows ------------------
__global__ __launch_bounds__(256) void ln_kernel(const float* __restrict__ src,
    bf16* __restrict__ dst, const float* __restrict__ g, const float* __restrict__ b,
    int Ls, int s0){
  int rr   = blockIdx.x * 4 + (threadIdx.x >> 6);
  int lane = threadIdx.x & 63;
  size_t off = rowOff(rr, Ls, s0) + (size_t)lane * 4;
  float4 v = *(const float4*)(src + off);
  float s = v.x + v.y + v.z + v.w;
  float q = v.x*v.x + v.y*v.y + v.z*v.z + v.w*v.w;
  #pragma unroll
  for (int d = 1; d < 64; d <<= 1){ s += __shfl_xor(s, d); q += __shfl_xor(q, d); }
  float m   = s * (1.0f/Dz);
  float rsd = rsqrtf(q * (1.0f/Dz) - m*m + 1e-5f);
  float4 gv = *(const float4*)(g + lane*4);
  float4 bv = *(const float4*)(b + lane*4);
  store4bf(dst + (size_t)rr*Dz + lane*4,
           (v.x-m)*rsd*gv.x + bv.x, (v.y-m)*rsd*gv.y + bv.y,
           (v.z-m)*rsd*gv.z + bv.z, (v.w-m)*rsd*gv.w + bv.w);
}

// ----------------- MFMA bf16 GEMM (BM=128, BN=256, BK=32, 8 waves) ---------
// 1D grid + XCD swizzle (ncols = N/256 col-blocks, col fastest in work order).
// A: bf16 [M x K] contiguous rows.  Wb: bf16 [N x K] (B^T).  N % 256 == 0.
// B-staging uses a 4x16-transpose column permutation within each 64-col group:
//   LDS row b holds global column (b&~63) + (b&15)*4 + ((b>>4)&3).
//   => lane fr's acc[.][n] covers 4 CONSECUTIVE global cols fr*4+n  -> b64 store.
// EPI: 0 = store bf16 (r*N+c), vectorized; bias segment = col when biasB!=null.
//      1 = f32 C[rowOff]=resid[rowOff]+v (N==256, ncols==1, LDS-transposed).
template<int EPI>
__global__ __launch_bounds__(512) void mgemm(
    const bf16* __restrict__ A, const bf16* __restrict__ Wb,
    const float* __restrict__ bias, const float* __restrict__ biasB,
    const float* __restrict__ biasC, void* __restrict__ Cp,
    const float* __restrict__ resid, const bf16* __restrict__ aux,
    int M, int N, int K, int cLs, int cS0, int ncols){
  __shared__ __align__(16) char smemraw[30720];
  bf16 (*As)[40] = reinterpret_cast<bf16(*)[40]>(smemraw);            // 128x40
  bf16 (*Bs)[40] = reinterpret_cast<bf16(*)[40]>(smemraw + 10240);    // 256x40
  const int tid  = threadIdx.x;
  const int lane = tid & 63;
  const int wave = tid >> 6;       // 0..7
  int rowb, colb;
  xcd_work(ncols, rowb, colb);
  const int r0 = rowb * 128;
  const int n0 = colb * 256;
  // staging: thread t -> A row t>>2 (one b128), B rows t>>2 and 128+(t>>2)
  const int srow = tid >> 2;           // 0..127
  const int scol = (tid & 3) * 8;      // 0,8,16,24
  // permuted global B-row for LDS row srow (and 128+srow)
  const int bprow = (srow & 64) + (srow & 15)*4 + ((srow >> 4) & 3);
  const bf16* ap  = A  + (size_t)(r0 + srow) * K + scol;
  const bf16* bp0 = Wb + (size_t)(n0 + bprow) * K + scol;
  const bf16* bp1 = Wb + (size_t)(n0 + 128 + bprow) * K + scol;
  // wave tile: 64x64 at (wr*64, wc*64); wr in {0,1}, wc in {0..3}
  const int wr = wave >> 2, wc = wave & 3;
  const int fr = lane & 15;
  const int fk = (lane >> 4) * 8;
  f32x4 acc[4][4] = {};
  for (int k0 = 0; k0 < K; k0 += 32){
    uint4 av  = *(const uint4*)(ap  + k0);
    uint4 bv0 = *(const uint4*)(bp0 + k0);
    uint4 bv1 = *(const uint4*)(bp1 + k0);
    __syncthreads();                 // prev iter's LDS reads done
    *(uint4*)&As[srow][scol]       = av;
    *(uint4*)&Bs[srow][scol]       = bv0;
    *(uint4*)&Bs[128 + srow][scol] = bv1;
    __syncthreads();
    short8v af[4], bf[4];
    #pragma unroll
    for (int m = 0; m < 4; ++m)
      af[m] = *(const short8v*)&As[wr*64 + m*16 + fr][fk];
    #pragma unroll
    for (int n = 0; n < 4; ++n)
      bf[n] = *(const short8v*)&Bs[wc*64 + n*16 + fr][fk];
    #pragma unroll
    for (int m = 0; m < 4; ++m)
      #pragma unroll
      for (int n = 0; n < 4; ++n)
        acc[m][n] = __builtin_amdgcn_mfma_f32_16x16x32_bf16(af[m], bf[n], acc[m][n], 0, 0, 0);
  }
  const int er = (lane >> 4) * 4;
  if (EPI == 1){
    // vectorized residual epilogue: stage 16 rows x 256 cols f32 in LDS
    // (stride 260 floats), then coalesced float4 resid-add + store.
    float* fsm = (float*)smemraw;       // 16*260*4 = 16640 B
    const int cb = wc*64 + fr*4;        // 4 consecutive cols per lane
    float bb0 = bias[cb], bb1 = bias[cb+1], bb2 = bias[cb+2], bb3 = bias[cb+3];
    #pragma unroll
    for (int m = 0; m < 4; ++m){
      #pragma unroll
      for (int wrs = 0; wrs < 2; ++wrs){
        __syncthreads();
        if (wr == wrs){
          #pragma unroll
          for (int j = 0; j < 4; ++j){
            float4 t;
            t.x = acc[m][0][j] + bb0; t.y = acc[m][1][j] + bb1;
            t.z = acc[m][2][j] + bb2; t.w = acc[m][3][j] + bb3;
            *(float4*)&fsm[(er + j)*260 + cb] = t;
          }
        }
        __syncthreads();
        int rrow = r0 + wrs*64 + m*16 + (tid >> 5);
        size_t ro = rowOff(rrow, cLs, cS0) + (size_t)(tid & 31)*8;
        const float* fs = fsm + (tid >> 5)*260 + (tid & 31)*8;
        float4 v0 = *(const float4*)(fs);
        float4 v1 = *(const float4*)(fs + 4);
        float4 q0 = *(const float4*)(resid + ro);
        float4 q1 = *(const float4*)(resid + ro + 4);
        v0.x += q0.x; v0.y += q0.y; v0.z += q0.z; v0.w += q0.w;
        v1.x += q1.x; v1.y += q1.y; v1.z += q1.z; v1.w += q1.w;
        *(float4*)((float*)Cp + ro)     = v0;
        *(float4*)((float*)Cp + ro + 4) = v1;
      }
    }
  } else {
    // vectorized bf16 store: lane fr owns cols cbase..cbase+3
    const float* bp = bias;
    if (biasB != nullptr) bp = (colb == 0) ? bias : ((colb == 1) ? biasB : biasC);
    const int cl = wc*64 + fr*4;
    float bb0 = bp[cl], bb1 = bp[cl+1], bb2 = bp[cl+2], bb3 = bp[cl+3];
    const int cbase = n0 + cl;
    #pragma unroll
    for (int m = 0; m < 4; ++m){
      #pragma unroll
      for (int j = 0; j < 4; ++j){
        int r = r0 + wr*64 + m*16 + er + j;
        store4bf(&((bf16*)Cp)[(size_t)r * N + cbase],
                 acc[m][0][j] + bb0, acc[m][1][j] + bb1,
                 acc[m][2][j] + bb2, acc[m][3][j] + bb3);
      }
    }
  }
}

// ----------------- fused dual GEMM for gated MLP up-projection -------------
// Hb[r][c] = (A.W1^T + b1) * silu(A.Wg^T + bg), N = 1024, shared A tile.
// 1D grid + XCD swizzle (8 col-blocks per row-block, col fastest).
// B-staging uses a 2x16-transpose permutation within each 32-col group:
//   LDS row b holds global column (b&~31) + (b&15)*2 + ((b>>4)&1)
//   => lane fr's acc[.][n] covers 2 consecutive cols fr*2+n -> b32 store.
__global__ __launch_bounds__(512) void mgemm_dual(
    const bf16* __restrict__ A, const bf16* __restrict__ W1b,
    const bf16* __restrict__ Wgb, const float* __restrict__ b1,
    const float* __restrict__ bg, bf16* __restrict__ Hb,
    int M, int K){
  __shared__ bf16 As[128][40];
  __shared__ bf16 B1s[128][40];
  __shared__ bf16 B2s[128][40];
  const int tid  = threadIdx.x;
  const int lane = tid & 63;
  const int wave = tid >> 6;       // 0..7
  int rowb, colb;
  xcd_work(8, rowb, colb);
  const int r0 = rowb * 128;
  const int n0 = colb * 128;
  const int srow = tid >> 2;           // 0..127
  const int scol = (tid & 3) * 8;      // 0,8,16,24
  const int bprow = (srow & ~31) + (srow & 15)*2 + ((srow >> 4) & 1);
  const bf16* ap = A   + (size_t)(r0 + srow) * K + scol;
  const bf16* p1 = W1b + (size_t)(n0 + bprow) * K + scol;
  const bf16* p2 = Wgb + (size_t)(n0 + bprow) * K + scol;
  // wave tile: 64 rows x 32 cols at (wr*64, wc*32)
  const int wr = wave >> 2, wc = wave & 3;
  const int fr = lane & 15;
  const int fk = (lane >> 4) * 8;
  f32x4 acc1[4][2] = {};
  f32x4 acc2[4][2] = {};
  for (int k0 = 0; k0 < K; k0 += 32){
    uint4 av = *(const uint4*)(ap + k0);
    uint4 v1 = *(const uint4*)(p1 + k0);
    uint4 v2 = *(const uint4*)(p2 + k0);
    __syncthreads();
    *(uint4*)&As[srow][scol]  = av;
    *(uint4*)&B1s[srow][scol] = v1;
    *(uint4*)&B2s[srow][scol] = v2;
    __syncthreads();
    short8v af[4], bf1[2], bf2[2];
    #pragma unroll
    for (int m = 0; m < 4; ++m)
      af[m] = *(const short8v*)&As[wr*64 + m*16 + fr][fk];
    #pragma unroll
    for (int n = 0; n < 2; ++n){
      bf1[n] = *(const short8v*)&B1s[wc*32 + n*16 + fr][fk];
      bf2[n] = *(const short8v*)&B2s[wc*32 + n*16 + fr][fk];
    }
    #pragma unroll
    for (int m = 0; m < 4; ++m)
      #pragma unroll
      for (int n = 0; n < 2; ++n){
        acc1[m][n] = __builtin_amdgcn_mfma_f32_16x16x32_bf16(af[m], bf1[n], acc1[m][n], 0, 0, 0);
        acc2[m][n] = __builtin_amdgcn_mfma_f32_16x16x32_bf16(af[m], bf2[n], acc2[m][n], 0, 0, 0);
      }
  }
  const int er = (lane >> 4) * 4;
  const int c = n0 + wc*32 + fr*2;
  const float b10 = b1[c], b11 = b1[c+1];
  const float bg0 = bg[c], bg1 = bg[c+1];
  #pragma unroll
  for (int m = 0; m < 4; ++m){
    #pragma unroll
    for (int j = 0; j < 4; ++j){
      int r = r0 + wr*64 + m*16 + er + j;
      float v0 = acc1[m][0][j] + b10;
      float g0 = acc2[m][0][j] + bg0;
      float v1 = acc1[m][1][j] + b11;
      float g1 = acc2[m][1][j] + bg1;
      float h0 = v0 * g0 / (1.0f + __expf(-g0));
      float h1 = v1 * g1 / (1.0f + __expf(-g1));
      store2bf(&Hb[(size_t)r * HIDz + c], h0, h1);
    }
  }
}

// ============== MFMA flash attention, train self-attn (L=256) ==============
// Block per (seq n, head h); 4 waves x 64 q-rows; flash over 4 KV blocks of 64.
// SWAPPED QK^T: s2 = mfma(K, Q) -> lane&15 = q, reduction axis lane-local.
__global__ __launch_bounds__(256) void attn_t_m(
    const bf16* __restrict__ Q, const bf16* __restrict__ K,
    const bf16* __restrict__ V, bf16* __restrict__ O, int ld){
  __shared__ bf16 Klds[64][40];
  __shared__ bf16 Vt[32][72];
  __shared__ bf16 Plds[4][64][72];
  const int n = blockIdx.x, h = blockIdx.y;
  const int tid = threadIdx.x, lane = tid & 63, w = tid >> 6;
  const size_t ibase = (size_t)n * 256 * ld + (size_t)h * 32;
  const size_t obase = (size_t)n * 256 * Dz + (size_t)h * 32;
  const int l15 = lane & 15, l4 = lane >> 4;
  short8v qf[4];
  #pragma unroll
  for (int m = 0; m < 4; ++m)
    qf[m] = *(const short8v*)(Q + ibase + (size_t)(w*64 + m*16 + l15) * ld + l4*8);
  f32x4 accO[4][2] = {};
  float mrowq[4], lrowq[4], sclq[4];
  #pragma unroll
  for (int m=0;m<4;++m){ mrowq[m] = -1e30f; lrowq[m] = 0.f; }
  const f32x4 zero = {};
  for (int kb = 0; kb < 4; ++kb){
    __syncthreads();
    {
      int r = tid >> 2, c8 = (tid & 3) * 8;
      *(uint4*)&Klds[r][c8] = *(const uint4*)(K + ibase + (size_t)(kb*64 + r) * ld + c8);
      uint4 vr = *(const uint4*)(V + ibase + (size_t)(kb*64 + r) * ld + c8);
      const bf16* vb = (const bf16*)&vr;
      #pragma unroll
      for (int i = 0; i < 8; ++i) Vt[c8 + i][r] = vb[i];
    }
    __syncthreads();
    short8v kf[4];
    #pragma unroll
    for (int nn = 0; nn < 4; ++nn)
      kf[nn] = *(const short8v*)&Klds[nn*16 + l15][l4*8];
    // swapped: s2[m][nn][j] = P[k=nn*16+l4*4+j][q=m*16+l15]
    f32x4 s2[4][4];
    #pragma unroll
    for (int m = 0; m < 4; ++m)
      #pragma unroll
      for (int nn = 0; nn < 4; ++nn)
        s2[m][nn] = __builtin_amdgcn_mfma_f32_16x16x32_bf16(kf[nn], qf[m], zero, 0,0,0);
    #pragma unroll
    for (int m = 0; m < 4; ++m){
      float mx = fmaxf(fmaxf(s2[m][0][0], s2[m][0][1]), fmaxf(s2[m][0][2], s2[m][0][3]));
      #pragma unroll
      for (int nn = 1; nn < 4; ++nn)
        mx = fmaxf(mx, fmaxf(fmaxf(s2[m][nn][0], s2[m][nn][1]),
                             fmaxf(s2[m][nn][2], s2[m][nn][3])));
      mx = fmaxf(mx, __shfl_xor(mx, 16));
      mx = fmaxf(mx, __shfl_xor(mx, 32));
      float mnew = fmaxf(mrowq[m], mx);
      float scl = __expf((mrowq[m] - mnew) * SCALE);
      mrowq[m] = mnew; sclq[m] = scl;
      float ps = 0.f;
      #pragma unroll
      for (int nn = 0; nn < 4; ++nn)
        #pragma unroll
        for (int j = 0; j < 4; ++j){
          float p = __expf((s2[m][nn][j] - mnew) * SCALE);
          s2[m][nn][j] = p; ps += p;
        }
      ps += __shfl_xor(ps, 16);
      ps += __shfl_xor(ps, 32);
      lrowq[m] = lrowq[m] * scl + ps;
    }
    // rescale accO (its q = m*16 + l4*4 + j; sclq lives on q = m*16 + l15)
    #pragma unroll
    for (int m = 0; m < 4; ++m)
      #pragma unroll
      for (int j = 0; j < 4; ++j){
        float so = __shfl(sclq[m], l4*4 + j);
        accO[m][0][j] *= so; accO[m][1][j] *= so;
      }
    // pack P into Plds [q][k]: j-contiguous -> one b64 store per (m,nn)
    #pragma unroll
    for (int m = 0; m < 4; ++m)
      #pragma unroll
      for (int nn = 0; nn < 4; ++nn)
        store4bf(&Plds[w][m*16 + l15][nn*16 + l4*4],
                 s2[m][nn][0], s2[m][nn][1], s2[m][nn][2], s2[m][nn][3]);
    #pragma unroll
    for (int m = 0; m < 4; ++m){
      #pragma unroll
      for (int kt = 0; kt < 2; ++kt){
        short8v pf = *(const short8v*)&Plds[w][m*16 + l15][kt*32 + l4*8];
        #pragma unroll
        for (int dt = 0; dt < 2; ++dt){
          short8v vf = *(const short8v*)&Vt[dt*16 + l15][kt*32 + l4*8];
          accO[m][dt] = __builtin_amdgcn_mfma_f32_16x16x32_bf16(pf, vf, accO[m][dt], 0,0,0);
        }
      }
    }
  }
  #pragma unroll
  for (int m = 0; m < 4; ++m){
    #pragma unroll
    for (int j = 0; j < 4; ++j){
      float inv = 1.0f / __shfl(lrowq[m], l4*4 + j);
      int row = w*64 + m*16 + l4*4 + j;
      #pragma unroll
      for (int dt = 0; dt < 2; ++dt)
        O[obase + (size_t)row * Dz + dt*16 + l15] = __float2bfloat16(accO[m][dt][j] * inv);
    }
  }
}

// ============== MFMA flash attention, wave-per-(row,head) ==================
// NKB = #key blocks of 64 (1 = feature attn, 4 = cross attn).
// MASK: hybrid additive mask applied for heads 0-3 only.
// grid (rows, 2): wave w handles head blockIdx.y*4 + w.  Swapped QK^T.
template<int NKB, int MASK>
__global__ __launch_bounds__(256) void attn_w(
    const bf16* __restrict__ Q, const bf16* __restrict__ K,
    const bf16* __restrict__ V, const float* __restrict__ mask,
    bf16* __restrict__ O, int ldq, int ldkv){
  __shared__ bf16 Klds[4][64][40];
  __shared__ bf16 Vt[4][32][72];
  __shared__ bf16 Plds[4][64][72];
  const int r = blockIdx.x;
  const int tid = threadIdx.x, lane = tid & 63, w = tid >> 6;
  const int h = blockIdx.y * 4 + w;
  const int l15 = lane & 15, l4 = lane >> 4;
  const size_t qoff = (size_t)r * 64 * ldq + (size_t)h * 32;
  const size_t koff = (size_t)r * (NKB*64) * ldkv + (size_t)h * 32;
  const size_t ooff = (size_t)r * 64 * Dz + (size_t)h * 32;
  short8v qf[4];
  #pragma unroll
  for (int m = 0; m < 4; ++m)
    qf[m] = *(const short8v*)(Q + qoff + (size_t)(m*16 + l15) * ldq + l4*8);
  f32x4 accO[4][2] = {};
  float mrowq[4], lrowq[4], sclq[4];
  #pragma unroll
  for (int m=0;m<4;++m){ mrowq[m] = -1e30f; lrowq[m] = 0.f; }
  const f32x4 zero = {};
  for (int kb = 0; kb < NKB; ++kb){
    {
      const bf16* kp = K + koff + (size_t)(kb*64 + lane) * ldkv;
      const bf16* vp = V + koff + (size_t)(kb*64 + lane) * ldkv;
      uint4 k0 = *(const uint4*)(kp);      uint4 k1 = *(const uint4*)(kp + 8);
      uint4 k2 = *(const uint4*)(kp + 16); uint4 k3 = *(const uint4*)(kp + 24);
      *(uint4*)&Klds[w][lane][0]  = k0; *(uint4*)&Klds[w][lane][8]  = k1;
      *(uint4*)&Klds[w][lane][16] = k2; *(uint4*)&Klds[w][lane][24] = k3;
      uint4 v0 = *(const uint4*)(vp);      uint4 v1 = *(const uint4*)(vp + 8);
      uint4 v2 = *(const uint4*)(vp + 16); uint4 v3 = *(const uint4*)(vp + 24);
      const bf16* vb0=(const bf16*)&v0; const bf16* vb1=(const bf16*)&v1;
      const bf16* vb2=(const bf16*)&v2; const bf16* vb3=(const bf16*)&v3;
      #pragma unroll
      for (int i = 0; i < 8; ++i){
        Vt[w][i][lane]      = vb0[i];
        Vt[w][8 + i][lane]  = vb1[i];
        Vt[w][16 + i][lane] = vb2[i];
        Vt[w][24 + i][lane] = vb3[i];
      }
    }
    short8v kf[4];
    #pragma unroll
    for (int nn = 0; nn < 4; ++nn)
      kf[nn] = *(const short8v*)&Klds[w][nn*16 + l15][l4*8];
    f32x4 s2[4][4];
    #pragma unroll
    for (int m = 0; m < 4; ++m)
      #pragma unroll
      for (int nn = 0; nn < 4; ++nn)
        s2[m][nn] = __builtin_amdgcn_mfma_f32_16x16x32_bf16(kf[nn], qf[m], zero, 0,0,0);
    if (MASK && h < 4){
      #pragma unroll
      for (int m = 0; m < 4; ++m)
        #pragma unroll
        for (int nn = 0; nn < 4; ++nn)
          #pragma unroll
          for (int j = 0; j < 4; ++j){
            int qq = m*16 + l15, kk = nn*16 + l4*4 + j;
            s2[m][nn][j] += (mask[qq*64 + kk] == 1.0f ? 0.0f : -1e30f);
          }
    }
    #pragma unroll
    for (int m = 0; m < 4; ++m){
      float mx = fmaxf(fmaxf(s2[m][0][0], s2[m][0][1]), fmaxf(s2[m][0][2], s2[m][0][3]));
      #pragma unroll
      for (int nn = 1; nn < 4; ++nn)
        mx = fmaxf(mx, fmaxf(fmaxf(s2[m][nn][0], s2[m][nn][1]),
                             fmaxf(s2[m][nn][2], s2[m][nn][3])));
      mx = fmaxf(mx, __shfl_xor(mx, 16));
      mx = fmaxf(mx, __shfl_xor(mx, 32));
      float mnew = fmaxf(mrowq[m], mx);
      float scl = __expf((mrowq[m] - mnew) * SCALE);
      mrowq[m] = mnew; sclq[m] = scl;
      float ps = 0.f;
      #pragma unroll
      for (int nn = 0; nn < 4; ++nn)
        #pragma unroll
        for (int j = 0; j < 4; ++j){
          float p = __expf((s2[m][nn][j] - mnew) * SCALE);
          s2[m][nn][j] = p; ps += p;
        }
      ps += __shfl_xor(ps, 16);
      ps += __shfl_xor(ps, 32);
      lrowq[m] = lrowq[m] * scl + ps;
    }
    #pragma unroll
    for (int m = 0; m < 4; ++m)
      #pragma unroll
      for (int j = 0; j < 4; ++j){
        float so = __shfl(sclq[m], l4*4 + j);
        accO[m][0][j] *= so; accO[m][1][j] *= so;
      }
    #pragma unroll
    for (int m = 0; m < 4; ++m)
      #pragma unroll
      for (int nn = 0; nn < 4; ++nn)
        store4bf(&Plds[w][m*16 + l15][nn*16 + l4*4],
                 s2[m][nn][0], s2[m][nn][1], s2[m][nn][2], s2[m][nn][3]);
    #pragma unroll
    for (int m = 0; m < 4; ++m){
      #pragma unroll
      for (int kt = 0; kt < 2; ++kt){
        short8v pf = *(const short8v*)&Plds[w][m*16 + l15][kt*32 + l4*8];
        #pragma unroll
        for (int dt = 0; dt < 2; ++dt){
          short8v vf = *(const short8v*)&Vt[w][dt*16 + l15][kt*32 + l4*8];
          accO[m][dt] = __builtin_amdgcn_mfma_f32_16x16x32_bf16(pf, vf, accO[m][dt], 0,0,0);
        }
      }
    }
  }
  #pragma unroll
  for (int m = 0; m < 4; ++m){
    #pragma unroll
    for (int j = 0; j < 4; ++j){
      float inv = 1.0f / __shfl(lrowq[m], l4*4 + j);
      int row = m*16 + l4*4 + j;
      #pragma unroll
      for (int dt = 0; dt < 2; ++dt)
        O[ooff + (size_t)row * Dz + dt*16 + l15] = __float2bfloat16(accO[m][dt][j] * inv);
    }
  }
}

// ---------------------------------------------------------------------------
extern "C" void kernel_launch(void* const* d_in, const int* in_sizes, int n_in,
                              void* d_out, int out_size, void* d_ws, size_t ws_size,
                              hipStream_t stream){
  (void)in_sizes; (void)n_in; (void)out_size; (void)ws_size;
  const float* x    = (const float*)d_in[0];
  const float* mask = (const float*)d_in[1];
  const float *Wqf=(const float*)d_in[2],  *Wkf=(const float*)d_in[3],
              *Wvf=(const float*)d_in[4],  *Wof=(const float*)d_in[5],
              *bqf=(const float*)d_in[6],  *bkf=(const float*)d_in[7],
              *bvf=(const float*)d_in[8],  *bof=(const float*)d_in[9],
              *gf =(const float*)d_in[10], *b2f=(const float*)d_in[11];
  const float *Wqt=(const float*)d_in[12], *Wkt=(const float*)d_in[13],
              *Wvt=(const float*)d_in[14], *Wot=(const float*)d_in[15],
              *bqt=(const float*)d_in[16], *bkt=(const float*)d_in[17],
              *bvt=(const float*)d_in[18], *bot=(const float*)d_in[19],
              *gt =(const float*)d_in[20], *b2t=(const float*)d_in[21];
  const float *Wqe=(const float*)d_in[22], *Wke=(const float*)d_in[23],
              *Wve=(const float*)d_in[24], *Woe=(const float*)d_in[25],
              *bqe=(const float*)d_in[26], *bke=(const float*)d_in[27],
              *bve=(const float*)d_in[28], *boe=(const float*)d_in[29],
              *ge =(const float*)d_in[30], *b2e=(const float*)d_in[31];
  const float *W1=(const float*)d_in[32], *b1=(const float*)d_in[33],
              *Wg=(const float*)d_in[34], *bg=(const float*)d_in[35],
              *W2=(const float*)d_in[36], *b2v=(const float*)d_in[37],
              *gm=(const float*)d_in[38], *bm=(const float*)d_in[39];

  float* Y = (float*)d_out;     // running activation in row layout (B,S,FN,D)

  char* wsb = (char*)d_ws;
  size_t off = 0;
  auto carve = [&](size_t bytes)->void*{
    void* p = wsb + off; off += (bytes + 255) & ~(size_t)255; return p;
  };
  bf16* Xn   = (bf16*)carve((size_t)TOK * Dz * 2);   // stage-specific LN'd activations
  bf16* QKVb = (bf16*)carve((size_t)TOK * 768 * 2);  // fused QKV
  bf16* Ob   = (bf16*)carve((size_t)TOK * Dz * 2);   // attention output
  bf16* Hb   = (bf16*)carve((size_t)CHD * HIDz * 2); // MLP fused-gate scratch (84 MB)
  // bf16 weights (fused QKV / KV; rest separate)
  bf16* WQKVf = (bf16*)carve((size_t)768*256*2);
  bf16* WQKVt = (bf16*)carve((size_t)768*256*2);
  bf16* WKVe  = (bf16*)carve((size_t)512*256*2);
  bf16* Wqeb  = (bf16*)carve((size_t)256*256*2);
  bf16* Wofb  = (bf16*)carve((size_t)256*256*2);
  bf16* Wotb  = (bf16*)carve((size_t)256*256*2);
  bf16* Woeb  = (bf16*)carve((size_t)256*256*2);
  bf16* W1b   = (bf16*)carve((size_t)HIDz*256*2);
  bf16* Wgb   = (bf16*)carve((size_t)HIDz*256*2);
  bf16* W2b   = (bf16*)carve((size_t)256*HIDz*2);

  const int DD = Dz*Dz;   // 65536
  {
    CvtArgs ca;
    const float* s12[12] = {Wqf,Wkf,Wvf, Wqt,Wkt,Wvt, Wke,Wve, Wqe,Wof,Wot,Woe};
    bf16* d12[12] = {WQKVf,WQKVf+DD,WQKVf+2*DD, WQKVt,WQKVt+DD,WQKVt+2*DD,
                     WKVe,WKVe+DD, Wqeb,Wofb,Wotb,Woeb};
    for (int i = 0; i < 12; ++i){ ca.src[i] = s12[i]; ca.dst[i] = d12[i]; }
    const float* sh[3] = {W1, Wg, W2};
    bf16* dh[3] = {W1b, Wgb, W2b};
    for (int j = 0; j < 3; ++j)
      for (int p = 0; p < 4; ++p){
        ca.src[12 + j*4 + p] = sh[j] + (size_t)p * DD;
        ca.dst[12 + j*4 + p] = dh[j] + (size_t)p * DD;
      }
    cvt_multi<<<dim3(DD/1024, 24), 256, 0, stream>>>(ca);
  }

  bf16* Qeb = QKVb + (size_t)TTR * 512;   // stage-C Q tile after KV rows

  // ---------------- Stage A: feature attention ----------------
  ln_kernel<<<TOK/4, 256, 0, stream>>>(x, Xn, gf, b2f, 0, 0);
  mgemm<0><<<3*(TOK/128), 512, 0, stream>>>(Xn, WQKVf, bqf, bkf, bvf, QKVb,
      nullptr, nullptr, TOK, 768, 256, 0,0, 3);
  attn_w<1,1><<<dim3(Bz*Sz, 2), 256, 0, stream>>>(QKVb, QKVb+256, QKVb+512, mask, Ob, 768, 768);
  mgemm<1><<<TOK/128, 512, 0, stream>>>(Ob, Wofb, bof, nullptr, nullptr, Y,
      x, nullptr, TOK, 256, 256, 0,0, 1);

  // ---------------- Stage B: train self-attention ----------------
  ln_kernel<<<TTR/4, 256, 0, stream>>>(Y, Xn, gt, b2t, NTRz, 0);
  mgemm<0><<<3*(TTR/128), 512, 0, stream>>>(Xn, WQKVt, bqt, bkt, bvt, QKVb,
      nullptr, nullptr, TTR, 768, 256, 0,0, 3);
  attn_t_m<<<dim3(NSEQ, 8), 256, 0, stream>>>(QKVb, QKVb+256, QKVb+512, Ob, 768);
  mgemm<1><<<TTR/128, 512, 0, stream>>>(Ob, Wotb, bot, nullptr, nullptr, Y,
      Y, nullptr, TTR, 256, 256, NTRz,0, 1);

  // ---------------- Stage C: cross attention ----------------
  ln_kernel<<<TTR/4, 256, 0, stream>>>(Y, Xn, ge, b2e, NTRz, 0);                      // kv rows
  ln_kernel<<<TTE/4, 256, 0, stream>>>(Y, Xn + (size_t)TTR*Dz, ge, b2e, NTEz, NTRz);  // query rows
  mgemm<0><<<TTE/128, 512, 0, stream>>>(Xn + (size_t)TTR*Dz, Wqeb, bqe,
      nullptr, nullptr, Qeb, nullptr, nullptr, TTE, 256, 256, 0,0, 1);
  mgemm<0><<<2*(TTR/128), 512, 0, stream>>>(Xn, WKVe, bke, bve, bve, QKVb,
      nullptr, nullptr, TTR, 512, 256, 0,0, 2);
  attn_w<4,0><<<dim3(NSEQ, 2), 256, 0, stream>>>(Qeb, QKVb, QKVb+256, nullptr, Ob, 256, 512);
  mgemm<1><<<TTE/128, 512, 0, stream>>>(Ob, Woeb, boe, nullptr, nullptr, Y,
      Y, nullptr, TTE, 256, 256, NTEz,NTRz, 1);

  // ---------------- Stage D: gated MLP (fused up-projection) ----------------
  ln_kernel<<<TOK/4, 256, 0, stream>>>(Y, Xn, gm, bm, 0, 0);
  for (int c = 0; c < TOK/CHD; ++c){
    const bf16* Anc = Xn + (size_t)c * CHD * Dz;
    float*      Yc  = Y  + (size_t)c * CHD * Dz;
    mgemm_dual<<<8*(CHD/128), 512, 0, stream>>>(Anc, W1b, Wgb, b1, bg,
        Hb, CHD, 256);
    mgemm<1><<<CHD/128, 512, 0, stream>>>(Hb, W2b, b2v, nullptr, nullptr,
        Yc, Yc, nullptr, CHD, 256, HIDz, 0,0, 1);
  }
}

// Round 20
// 708.044 us; speedup vs baseline: 1.0817x; 1.0175x over previous
//
#include <hip/hip_runtime.h>
#include <hip/hip_bf16.h>

typedef __hip_bfloat16 bf16;
typedef __attribute__((ext_vector_type(8))) short short8v;
typedef __attribute__((ext_vector_type(4))) float f32x4;

#define Bz   4
#define Sz   320
#define FNz  64
#define Dz   256
#define HIDz 1024
#define TOK  (Bz*Sz*FNz)     // 81920 tokens
#define NSEQ (Bz*FNz)        // 256 column sequences
#define NTRz 256
#define NTEz 64
#define TTR  (NSEQ*NTRz)     // 65536 train tokens
#define TTE  (NSEQ*NTEz)     // 16384 test tokens
#define CHD  40960           // stage-D chunk (tokens)
#define SCALE 0.17677669529663687f   // 1/sqrt(32)

// Map a "column-view" token rr (sequence-major) to its element offset in the
// row-layout (B,S,FN,D) tensor. Ls==0 -> plain contiguous rows of 256.
__device__ __forceinline__ size_t rowOff(int rr, int Ls, int s0){
  if (Ls == 0) return (size_t)rr * Dz;
  int n = rr / Ls;              // n = b*FN + f
  int s = rr - n * Ls + s0;
  return (((size_t)(n >> 6) * Sz + s) * FNz + (n & 63)) * Dz;
}

__device__ __forceinline__ void store4bf(bf16* p, float a, float b, float c, float d){
  bf16 t0=__float2bfloat16(a), t1=__float2bfloat16(b),
       t2=__float2bfloat16(c), t3=__float2bfloat16(d);
  ushort4 u;
  u.x=*(unsigned short*)&t0; u.y=*(unsigned short*)&t1;
  u.z=*(unsigned short*)&t2; u.w=*(unsigned short*)&t3;
  *(ushort4*)p = u;
}

__device__ __forceinline__ void store2bf(bf16* p, float a, float b){
  bf16 t0=__float2bfloat16(a), t1=__float2bfloat16(b);
  ushort2 u;
  u.x=*(unsigned short*)&t0; u.y=*(unsigned short*)&t1;
  *(ushort2*)p = u;
}

// XCD-aware swizzle: dispatch L -> work W; each XCD (L&7) owns a contiguous
// row-major work chunk, so col-blocks sharing an A-tile are time-adjacent on
// the SAME XCD (A-tile L2-resident).  nwg % 8 == 0 required.
__device__ __forceinline__ void xcd_work(int ncols, int& row, int& col){
  int L   = blockIdx.x;
  int cpx = gridDim.x >> 3;
  int W   = (L & 7) * cpx + (L >> 3);
  row = W / ncols;
  col = W - row * ncols;
}

// ----------------- f32 -> bf16 weight conversion (all weights, one launch) --
struct CvtArgs { const float* src[24]; bf16* dst[24]; };
__global__ __launch_bounds__(256) void cvt_multi(CvtArgs args){
  int i = (blockIdx.x * 256 + threadIdx.x) * 4;
  const float* s = args.src[blockIdx.y];
  bf16*        d = args.dst[blockIdx.y];
  float4 v = *(const float4*)(s + i);
  store4bf(d + i, v.x, v.y, v.z, v.w);
}

// ----------------- fused LayerNorm -> contiguous bf16 rows ------------------
__global__ __launch_bounds__(256) void ln_kernel(const float* __restrict__ src,
    bf16* __restrict__ dst, const float* __restrict__ g, const float* __restrict__ b,
    int Ls, int s0){
  int rr   = blockIdx.x * 4 + (threadIdx.x >> 6);
  int lane = threadIdx.x & 63;
  size_t off = rowOff(rr, Ls, s0) + (size_t)lane * 4;
  float4 v = *(const float4*)(src + off);
  float s = v.x + v.y + v.z + v.w;
  float q = v.x*v.x + v.y*v.y + v.z*v.z + v.w*v.w;
  #pragma unroll
  for (int d = 1; d < 64; d <<= 1){ s += __shfl_xor(s, d); q += __shfl_xor(q, d); }
  float m   = s * (1.0f/Dz);
  float rsd = rsqrtf(q * (1.0f/Dz) - m*m + 1e-5f);
  float4 gv = *(const float4*)(g + lane*4);
  float4 bv = *(const float4*)(b + lane*4);
  store4bf(dst + (size_t)rr*Dz + lane*4,
           (v.x-m)*rsd*gv.x + bv.x, (v.y-m)*rsd*gv.y + bv.y,
           (v.z-m)*rsd*gv.z + bv.z, (v.w-m)*rsd*gv.w + bv.w);
}

// ----------------- MFMA bf16 GEMM (BM=128, BN=256, BK=32, 8 waves) ---------
// 1D grid + XCD swizzle (ncols = N/256 col-blocks, col fastest in work order).
// A: bf16 [M x K] contiguous rows.  Wb: bf16 [N x K] (B^T).  N % 256 == 0.
// T14 async-STAGE split: iteration k+1's global loads are issued right after
// the second barrier, covered by the MFMA cluster of iteration k.
// B-staging uses a 4x16-transpose column permutation within each 64-col group
// => lane fr's acc[.][n] covers 4 CONSECUTIVE global cols fr*4+n -> b64 store.
// EPI: 0 = store bf16 (r*N+c), vectorized; bias segment = col when biasB!=null.
//      1 = f32 C[rowOff]=resid[rowOff]+v (N==256, ncols==1, LDS-transposed).
template<int EPI>
__global__ __launch_bounds__(512) void mgemm(
    const bf16* __restrict__ A, const bf16* __restrict__ Wb,
    const float* __restrict__ bias, const float* __restrict__ biasB,
    const float* __restrict__ biasC, void* __restrict__ Cp,
    const float* __restrict__ resid, const bf16* __restrict__ aux,
    int M, int N, int K, int cLs, int cS0, int ncols){
  __shared__ __align__(16) char smemraw[30720];
  bf16 (*As)[40] = reinterpret_cast<bf16(*)[40]>(smemraw);            // 128x40
  bf16 (*Bs)[40] = reinterpret_cast<bf16(*)[40]>(smemraw + 10240);    // 256x40
  const int tid  = threadIdx.x;
  const int lane = tid & 63;
  const int wave = tid >> 6;       // 0..7
  int rowb, colb;
  xcd_work(ncols, rowb, colb);
  const int r0 = rowb * 128;
  const int n0 = colb * 256;
  // staging: thread t -> A row t>>2 (one b128), B rows t>>2 and 128+(t>>2)
  const int srow = tid >> 2;           // 0..127
  const int scol = (tid & 3) * 8;      // 0,8,16,24
  // permuted global B-row for LDS row srow (and 128+srow)
  const int bprow = (srow & 64) + (srow & 15)*4 + ((srow >> 4) & 3);
  const bf16* ap  = A  + (size_t)(r0 + srow) * K + scol;
  const bf16* bp0 = Wb + (size_t)(n0 + bprow) * K + scol;
  const bf16* bp1 = Wb + (size_t)(n0 + 128 + bprow) * K + scol;
  // wave tile: 64x64 at (wr*64, wc*64); wr in {0,1}, wc in {0..3}
  const int wr = wave >> 2, wc = wave & 3;
  const int fr = lane & 15;
  const int fk = (lane >> 4) * 8;
  f32x4 acc[4][4] = {};
  // prologue: load K-slab 0
  uint4 av  = *(const uint4*)(ap);
  uint4 bv0 = *(const uint4*)(bp0);
  uint4 bv1 = *(const uint4*)(bp1);
  for (int k0 = 0; k0 < K; k0 += 32){
    __syncthreads();                 // prev iter's LDS reads done
    *(uint4*)&As[srow][scol]       = av;
    *(uint4*)&Bs[srow][scol]       = bv0;
    *(uint4*)&Bs[128 + srow][scol] = bv1;
    __syncthreads();
    if (k0 + 32 < K){                // T14: issue next-slab loads early;
      av  = *(const uint4*)(ap  + k0 + 32);   // HBM/L2 latency hides under
      bv0 = *(const uint4*)(bp0 + k0 + 32);   // the MFMA cluster below
      bv1 = *(const uint4*)(bp1 + k0 + 32);
    }
    short8v af[4], bf[4];
    #pragma unroll
    for (int m = 0; m < 4; ++m)
      af[m] = *(const short8v*)&As[wr*64 + m*16 + fr][fk];
    #pragma unroll
    for (int n = 0; n < 4; ++n)
      bf[n] = *(const short8v*)&Bs[wc*64 + n*16 + fr][fk];
    #pragma unroll
    for (int m = 0; m < 4; ++m)
      #pragma unroll
      for (int n = 0; n < 4; ++n)
        acc[m][n] = __builtin_amdgcn_mfma_f32_16x16x32_bf16(af[m], bf[n], acc[m][n], 0, 0, 0);
  }
  const int er = (lane >> 4) * 4;
  if (EPI == 1){
    // vectorized residual epilogue: stage 16 rows x 256 cols f32 in LDS
    // (stride 260 floats), then coalesced float4 resid-add + store.
    float* fsm = (float*)smemraw;       // 16*260*4 = 16640 B
    const int cb = wc*64 + fr*4;        // 4 consecutive cols per lane
    float bb0 = bias[cb], bb1 = bias[cb+1], bb2 = bias[cb+2], bb3 = bias[cb+3];
    #pragma unroll
    for (int m = 0; m < 4; ++m){
      #pragma unroll
      for (int wrs = 0; wrs < 2; ++wrs){
        __syncthreads();
        if (wr == wrs){
          #pragma unroll
          for (int j = 0; j < 4; ++j){
            float4 t;
            t.x = acc[m][0][j] + bb0; t.y = acc[m][1][j] + bb1;
            t.z = acc[m][2][j] + bb2; t.w = acc[m][3][j] + bb3;
            *(float4*)&fsm[(er + j)*260 + cb] = t;
          }
        }
        __syncthreads();
        int rrow = r0 + wrs*64 + m*16 + (tid >> 5);
        size_t ro = rowOff(rrow, cLs, cS0) + (size_t)(tid & 31)*8;
        const float* fs = fsm + (tid >> 5)*260 + (tid & 31)*8;
        float4 v0 = *(const float4*)(fs);
        float4 v1 = *(const float4*)(fs + 4);
        float4 q0 = *(const float4*)(resid + ro);
        float4 q1 = *(const float4*)(resid + ro + 4);
        v0.x += q0.x; v0.y += q0.y; v0.z += q0.z; v0.w += q0.w;
        v1.x += q1.x; v1.y += q1.y; v1.z += q1.z; v1.w += q1.w;
        *(float4*)((float*)Cp + ro)     = v0;
        *(float4*)((float*)Cp + ro + 4) = v1;
      }
    }
  } else {
    // vectorized bf16 store: lane fr owns cols cbase..cbase+3
    const float* bp = bias;
    if (biasB != nullptr) bp = (colb == 0) ? bias : ((colb == 1) ? biasB : biasC);
    const int cl = wc*64 + fr*4;
    float bb0 = bp[cl], bb1 = bp[cl+1], bb2 = bp[cl+2], bb3 = bp[cl+3];
    const int cbase = n0 + cl;
    #pragma unroll
    for (int m = 0; m < 4; ++m){
      #pragma unroll
      for (int j = 0; j < 4; ++j){
        int r = r0 + wr*64 + m*16 + er + j;
        store4bf(&((bf16*)Cp)[(size_t)r * N + cbase],
                 acc[m][0][j] + bb0, acc[m][1][j] + bb1,
                 acc[m][2][j] + bb2, acc[m][3][j] + bb3);
      }
    }
  }
}

// ----------------- fused dual GEMM for gated MLP up-projection -------------
// Hb[r][c] = (A.W1^T + b1) * silu(A.Wg^T + bg), N = 1024, shared A tile.
// 1D grid + XCD swizzle (8 col-blocks per row-block, col fastest).
// T14 async-STAGE split as in mgemm.
// B-staging uses a 2x16-transpose permutation within each 32-col group
// => lane fr's acc[.][n] covers 2 consecutive cols fr*2+n -> b32 store.
__global__ __launch_bounds__(512) void mgemm_dual(
    const bf16* __restrict__ A, const bf16* __restrict__ W1b,
    const bf16* __restrict__ Wgb, const float* __restrict__ b1,
    const float* __restrict__ bg, bf16* __restrict__ Hb,
    int M, int K){
  __shared__ bf16 As[128][40];
  __shared__ bf16 B1s[128][40];
  __shared__ bf16 B2s[128][40];
  const int tid  = threadIdx.x;
  const int lane = tid & 63;
  const int wave = tid >> 6;       // 0..7
  int rowb, colb;
  xcd_work(8, rowb, colb);
  const int r0 = rowb * 128;
  const int n0 = colb * 128;
  const int srow = tid >> 2;           // 0..127
  const int scol = (tid & 3) * 8;      // 0,8,16,24
  const int bprow = (srow & ~31) + (srow & 15)*2 + ((srow >> 4) & 1);
  const bf16* ap = A   + (size_t)(r0 + srow) * K + scol;
  const bf16* p1 = W1b + (size_t)(n0 + bprow) * K + scol;
  const bf16* p2 = Wgb + (size_t)(n0 + bprow) * K + scol;
  // wave tile: 64 rows x 32 cols at (wr*64, wc*32)
  const int wr = wave >> 2, wc = wave & 3;
  const int fr = lane & 15;
  const int fk = (lane >> 4) * 8;
  f32x4 acc1[4][2] = {};
  f32x4 acc2[4][2] = {};
  // prologue: load K-slab 0
  uint4 av = *(const uint4*)(ap);
  uint4 v1 = *(const uint4*)(p1);
  uint4 v2 = *(const uint4*)(p2);
  for (int k0 = 0; k0 < K; k0 += 32){
    __syncthreads();
    *(uint4*)&As[srow][scol]  = av;
    *(uint4*)&B1s[srow][scol] = v1;
    *(uint4*)&B2s[srow][scol] = v2;
    __syncthreads();
    if (k0 + 32 < K){                // T14 early issue, covered by MFMA
      av = *(const uint4*)(ap + k0 + 32);
      v1 = *(const uint4*)(p1 + k0 + 32);
      v2 = *(const uint4*)(p2 + k0 + 32);
    }
    short8v af[4], bf1[2], bf2[2];
    #pragma unroll
    for (int m = 0; m < 4; ++m)
      af[m] = *(const short8v*)&As[wr*64 + m*16 + fr][fk];
    #pragma unroll
    for (int n = 0; n < 2; ++n){
      bf1[n] = *(const short8v*)&B1s[wc*32 + n*16 + fr][fk];
      bf2[n] = *(const short8v*)&B2s[wc*32 + n*16 + fr][fk];
    }
    #pragma unroll
    for (int m = 0; m < 4; ++m)
      #pragma unroll
      for (int n = 0; n < 2; ++n){
        acc1[m][n] = __builtin_amdgcn_mfma_f32_16x16x32_bf16(af[m], bf1[n], acc1[m][n], 0, 0, 0);
        acc2[m][n] = __builtin_amdgcn_mfma_f32_16x16x32_bf16(af[m], bf2[n], acc2[m][n], 0, 0, 0);
      }
  }
  const int er = (lane >> 4) * 4;
  const int c = n0 + wc*32 + fr*2;
  const float b10 = b1[c], b11 = b1[c+1];
  const float bg0 = bg[c], bg1 = bg[c+1];
  #pragma unroll
  for (int m = 0; m < 4; ++m){
    #pragma unroll
    for (int j = 0; j < 4; ++j){
      int r = r0 + wr*64 + m*16 + er + j;
      float v0 = acc1[m][0][j] + b10;
      float g0 = acc2[m][0][j] + bg0;
      float w1 = acc1[m][1][j] + b11;
      float g1 = acc2[m][1][j] + bg1;
      float h0 = v0 * g0 / (1.0f + __expf(-g0));
      float h1 = w1 * g1 / (1.0f + __expf(-g1));
      store2bf(&Hb[(size_t)r * HIDz + c], h0, h1);
    }
  }
}

// ============== MFMA flash attention, train self-attn (L=256) ==============
// Block per (seq n, head h); 4 waves x 64 q-rows; flash over 4 KV blocks of 64.
// SWAPPED QK^T: s2 = mfma(K, Q) -> lane&15 = q, reduction axis lane-local.
__global__ __launch_bounds__(256) void attn_t_m(
    const bf16* __restrict__ Q, const bf16* __restrict__ K,
    const bf16* __restrict__ V, bf16* __restrict__ O, int ld){
  __shared__ bf16 Klds[64][40];
  __shared__ bf16 Vt[32][72];
  __shared__ bf16 Plds[4][64][72];
  const int n = blockIdx.x, h = blockIdx.y;
  const int tid = threadIdx.x, lane = tid & 63, w = tid >> 6;
  const size_t ibase = (size_t)n * 256 * ld + (size_t)h * 32;
  const size_t obase = (size_t)n * 256 * Dz + (size_t)h * 32;
  const int l15 = lane & 15, l4 = lane >> 4;
  short8v qf[4];
  #pragma unroll
  for (int m = 0; m < 4; ++m)
    qf[m] = *(const short8v*)(Q + ibase + (size_t)(w*64 + m*16 + l15) * ld + l4*8);
  f32x4 accO[4][2] = {};
  float mrowq[4], lrowq[4], sclq[4];
  #pragma unroll
  for (int m=0;m<4;++m){ mrowq[m] = -1e30f; lrowq[m] = 0.f; }
  const f32x4 zero = {};
  for (int kb = 0; kb < 4; ++kb){
    __syncthreads();
    {
      int r = tid >> 2, c8 = (tid & 3) * 8;
      *(uint4*)&Klds[r][c8] = *(const uint4*)(K + ibase + (size_t)(kb*64 + r) * ld + c8);
      uint4 vr = *(const uint4*)(V + ibase + (size_t)(kb*64 + r) * ld + c8);
      const bf16* vb = (const bf16*)&vr;
      #pragma unroll
      for (int i = 0; i < 8; ++i) Vt[c8 + i][r] = vb[i];
    }
    __syncthreads();
    short8v kf[4];
    #pragma unroll
    for (int nn = 0; nn < 4; ++nn)
      kf[nn] = *(const short8v*)&Klds[nn*16 + l15][l4*8];
    // swapped: s2[m][nn][j] = P[k=nn*16+l4*4+j][q=m*16+l15]
    f32x4 s2[4][4];
    #pragma unroll
    for (int m = 0; m < 4; ++m)
      #pragma unroll
      for (int nn = 0; nn < 4; ++nn)
        s2[m][nn] = __builtin_amdgcn_mfma_f32_16x16x32_bf16(kf[nn], qf[m], zero, 0,0,0);
    #pragma unroll
    for (int m = 0; m < 4; ++m){
      float mx = fmaxf(fmaxf(s2[m][0][0], s2[m][0][1]), fmaxf(s2[m][0][2], s2[m][0][3]));
      #pragma unroll
      for (int nn = 1; nn < 4; ++nn)
        mx = fmaxf(mx, fmaxf(fmaxf(s2[m][nn][0], s2[m][nn][1]),
                             fmaxf(s2[m][nn][2], s2[m][nn][3])));
      mx = fmaxf(mx, __shfl_xor(mx, 16));
      mx = fmaxf(mx, __shfl_xor(mx, 32));
      float mnew = fmaxf(mrowq[m], mx);
      float scl = __expf((mrowq[m] - mnew) * SCALE);
      mrowq[m] = mnew; sclq[m] = scl;
      float ps = 0.f;
      #pragma unroll
      for (int nn = 0; nn < 4; ++nn)
        #pragma unroll
        for (int j = 0; j < 4; ++j){
          float p = __expf((s2[m][nn][j] - mnew) * SCALE);
          s2[m][nn][j] = p; ps += p;
        }
      ps += __shfl_xor(ps, 16);
      ps += __shfl_xor(ps, 32);
      lrowq[m] = lrowq[m] * scl + ps;
    }
    // rescale accO (its q = m*16 + l4*4 + j; sclq lives on q = m*16 + l15)
    #pragma unroll
    for (int m = 0; m < 4; ++m)
      #pragma unroll
      for (int j = 0; j < 4; ++j){
        float so = __shfl(sclq[m], l4*4 + j);
        accO[m][0][j] *= so; accO[m][1][j] *= so;
      }
    // pack P into Plds [q][k]: j-contiguous -> one b64 store per (m,nn)
    #pragma unroll
    for (int m = 0; m < 4; ++m)
      #pragma unroll
      for (int nn = 0; nn < 4; ++nn)
        store4bf(&Plds[w][m*16 + l15][nn*16 + l4*4],
                 s2[m][nn][0], s2[m][nn][1], s2[m][nn][2], s2[m][nn][3]);
    #pragma unroll
    for (int m = 0; m < 4; ++m){
      #pragma unroll
      for (int kt = 0; kt < 2; ++kt){
        short8v pf = *(const short8v*)&Plds[w][m*16 + l15][kt*32 + l4*8];
        #pragma unroll
        for (int dt = 0; dt < 2; ++dt){
          short8v vf = *(const short8v*)&Vt[dt*16 + l15][kt*32 + l4*8];
          accO[m][dt] = __builtin_amdgcn_mfma_f32_16x16x32_bf16(pf, vf, accO[m][dt], 0,0,0);
        }
      }
    }
  }
  #pragma unroll
  for (int m = 0; m < 4; ++m){
    #pragma unroll
    for (int j = 0; j < 4; ++j){
      float inv = 1.0f / __shfl(lrowq[m], l4*4 + j);
      int row = w*64 + m*16 + l4*4 + j;
      #pragma unroll
      for (int dt = 0; dt < 2; ++dt)
        O[obase + (size_t)row * Dz + dt*16 + l15] = __float2bfloat16(accO[m][dt][j] * inv);
    }
  }
}

// ============== MFMA flash attention, wave-per-(row,head) ==================
// NKB = #key blocks of 64 (1 = feature attn, 4 = cross attn).
// MASK: hybrid additive mask applied for heads 0-3 only.
// grid (rows, 2): wave w handles head blockIdx.y*4 + w.  Swapped QK^T.
template<int NKB, int MASK>
__global__ __launch_bounds__(256) void attn_w(
    const bf16* __restrict__ Q, const bf16* __restrict__ K,
    const bf16* __restrict__ V, const float* __restrict__ mask,
    bf16* __restrict__ O, int ldq, int ldkv){
  __shared__ bf16 Klds[4][64][40];
  __shared__ bf16 Vt[4][32][72];
  __shared__ bf16 Plds[4][64][72];
  const int r = blockIdx.x;
  const int tid = threadIdx.x, lane = tid & 63, w = tid >> 6;
  const int h = blockIdx.y * 4 + w;
  const int l15 = lane & 15, l4 = lane >> 4;
  const size_t qoff = (size_t)r * 64 * ldq + (size_t)h * 32;
  const size_t koff = (size_t)r * (NKB*64) * ldkv + (size_t)h * 32;
  const size_t ooff = (size_t)r * 64 * Dz + (size_t)h * 32;
  short8v qf[4];
  #pragma unroll
  for (int m = 0; m < 4; ++m)
    qf[m] = *(const short8v*)(Q + qoff + (size_t)(m*16 + l15) * ldq + l4*8);
  f32x4 accO[4][2] = {};
  float mrowq[4], lrowq[4], sclq[4];
  #pragma unroll
  for (int m=0;m<4;++m){ mrowq[m] = -1e30f; lrowq[m] = 0.f; }
  const f32x4 zero = {};
  for (int kb = 0; kb < NKB; ++kb){
    {
      const bf16* kp = K + koff + (size_t)(kb*64 + lane) * ldkv;
      const bf16* vp = V + koff + (size_t)(kb*64 + lane) * ldkv;
      uint4 k0 = *(const uint4*)(kp);      uint4 k1 = *(const uint4*)(kp + 8);
      uint4 k2 = *(const uint4*)(kp + 16); uint4 k3 = *(const uint4*)(kp + 24);
      *(uint4*)&Klds[w][lane][0]  = k0; *(uint4*)&Klds[w][lane][8]  = k1;
      *(uint4*)&Klds[w][lane][16] = k2; *(uint4*)&Klds[w][lane][24] = k3;
      uint4 v0 = *(const uint4*)(vp);      uint4 v1 = *(const uint4*)(vp + 8);
      uint4 v2 = *(const uint4*)(vp + 16); uint4 v3 = *(const uint4*)(vp + 24);
      const bf16* vb0=(const bf16*)&v0; const bf16* vb1=(const bf16*)&v1;
      const bf16* vb2=(const bf16*)&v2; const bf16* vb3=(const bf16*)&v3;
      #pragma unroll
      for (int i = 0; i < 8; ++i){
        Vt[w][i][lane]      = vb0[i];
        Vt[w][8 + i][lane]  = vb1[i];
        Vt[w][16 + i][lane] = vb2[i];
        Vt[w][24 + i][lane] = vb3[i];
      }
    }
    short8v kf[4];
    #pragma unroll
    for (int nn = 0; nn < 4; ++nn)
      kf[nn] = *(const short8v*)&Klds[w][nn*16 + l15][l4*8];
    f32x4 s2[4][4];
    #pragma unroll
    for (int m = 0; m < 4; ++m)
      #pragma unroll
      for (int nn = 0; nn < 4; ++nn)
        s2[m][nn] = __builtin_amdgcn_mfma_f32_16x16x32_bf16(kf[nn], qf[m], zero, 0,0,0);
    if (MASK && h < 4){
      #pragma unroll
      for (int m = 0; m < 4; ++m)
        #pragma unroll
        for (int nn = 0; nn < 4; ++nn)
          #pragma unroll
          for (int j = 0; j < 4; ++j){
            int qq = m*16 + l15, kk = nn*16 + l4*4 + j;
            s2[m][nn][j] += (mask[qq*64 + kk] == 1.0f ? 0.0f : -1e30f);
          }
    }
    #pragma unroll
    for (int m = 0; m < 4; ++m){
      float mx = fmaxf(fmaxf(s2[m][0][0], s2[m][0][1]), fmaxf(s2[m][0][2], s2[m][0][3]));
      #pragma unroll
      for (int nn = 1; nn < 4; ++nn)
        mx = fmaxf(mx, fmaxf(fmaxf(s2[m][nn][0], s2[m][nn][1]),
                             fmaxf(s2[m][nn][2], s2[m][nn][3])));
      mx = fmaxf(mx, __shfl_xor(mx, 16));
      mx = fmaxf(mx, __shfl_xor(mx, 32));
      float mnew = fmaxf(mrowq[m], mx);
      float scl = __expf((mrowq[m] - mnew) * SCALE);
      mrowq[m] = mnew; sclq[m] = scl;
      float ps = 0.f;
      #pragma unroll
      for (int nn = 0; nn < 4; ++nn)
        #pragma unroll
        for (int j = 0; j < 4; ++j){
          float p = __expf((s2[m][nn][j] - mnew) * SCALE);
          s2[m][nn][j] = p; ps += p;
        }
      ps += __shfl_xor(ps, 16);
      ps += __shfl_xor(ps, 32);
      lrowq[m] = lrowq[m] * scl + ps;
    }
    #pragma unroll
    for (int m = 0; m < 4; ++m)
      #pragma unroll
      for (int j = 0; j < 4; ++j){
        float so = __shfl(sclq[m], l4*4 + j);
        accO[m][0][j] *= so; accO[m][1][j] *= so;
      }
    #pragma unroll
    for (int m = 0; m < 4; ++m)
      #pragma unroll
      for (int nn = 0; nn < 4; ++nn)
        store4bf(&Plds[w][m*16 + l15][nn*16 + l4*4],
                 s2[m][nn][0], s2[m][nn][1], s2[m][nn][2], s2[m][nn][3]);
    #pragma unroll
    for (int m = 0; m < 4; ++m){
      #pragma unroll
      for (int kt = 0; kt < 2; ++kt){
        short8v pf = *(const short8v*)&Plds[w][m*16 + l15][kt*32 + l4*8];
        #pragma unroll
        for (int dt = 0; dt < 2; ++dt){
          short8v vf = *(const short8v*)&Vt[w][dt*16 + l15][kt*32 + l4*8];
          accO[m][dt] = __builtin_amdgcn_mfma_f32_16x16x32_bf16(pf, vf, accO[m][dt], 0,0,0);
        }
      }
    }
  }
  #pragma unroll
  for (int m = 0; m < 4; ++m){
    #pragma unroll
    for (int j = 0; j < 4; ++j){
      float inv = 1.0f / __shfl(lrowq[m], l4*4 + j);
      int row = m*16 + l4*4 + j;
      #pragma unroll
      for (int dt = 0; dt < 2; ++dt)
        O[ooff + (size_t)row * Dz + dt*16 + l15] = __float2bfloat16(accO[m][dt][j] * inv);
    }
  }
}

// ---------------------------------------------------------------------------
extern "C" void kernel_launch(void* const* d_in, const int* in_sizes, int n_in,
                              void* d_out, int out_size, void* d_ws, size_t ws_size,
                              hipStream_t stream){
  (void)in_sizes; (void)n_in; (void)out_size; (void)ws_size;
  const float* x    = (const float*)d_in[0];
  const float* mask = (const float*)d_in[1];
  const float *Wqf=(const float*)d_in[2],  *Wkf=(const float*)d_in[3],
              *Wvf=(const float*)d_in[4],  *Wof=(const float*)d_in[5],
              *bqf=(const float*)d_in[6],  *bkf=(const float*)d_in[7],
              *bvf=(const float*)d_in[8],  *bof=(const float*)d_in[9],
              *gf =(const float*)d_in[10], *b2f=(const float*)d_in[11];
  const float *Wqt=(const float*)d_in[12], *Wkt=(const float*)d_in[13],
              *Wvt=(const float*)d_in[14], *Wot=(const float*)d_in[15],
              *bqt=(const float*)d_in[16], *bkt=(const float*)d_in[17],
              *bvt=(const float*)d_in[18], *bot=(const float*)d_in[19],
              *gt =(const float*)d_in[20], *b2t=(const float*)d_in[21];
  const float *Wqe=(const float*)d_in[22], *Wke=(const float*)d_in[23],
              *Wve=(const float*)d_in[24], *Woe=(const float*)d_in[25],
              *bqe=(const float*)d_in[26], *bke=(const float*)d_in[27],
              *bve=(const float*)d_in[28], *boe=(const float*)d_in[29],
              *ge =(const float*)d_in[30], *b2e=(const float*)d_in[31];
  const float *W1=(const float*)d_in[32], *b1=(const float*)d_in[33],
              *Wg=(const float*)d_in[34], *bg=(const float*)d_in[35],
              *W2=(const float*)d_in[36], *b2v=(const float*)d_in[37],
              *gm=(const float*)d_in[38], *bm=(const float*)d_in[39];

  float* Y = (float*)d_out;     // running activation in row layout (B,S,FN,D)

  char* wsb = (char*)d_ws;
  size_t off = 0;
  auto carve = [&](size_t bytes)->void*{
    void* p = wsb + off; off += (bytes + 255) & ~(size_t)255; return p;
  };
  bf16* Xn   = (bf16*)carve((size_t)TOK * Dz * 2);   // stage-specific LN'd activations
  bf16* QKVb = (bf16*)carve((size_t)TOK * 768 * 2);  // fused QKV
  bf16* Ob   = (bf16*)carve((size_t)TOK * Dz * 2);   // attention output
  bf16* Hb   = (bf16*)carve((size_t)CHD * HIDz * 2); // MLP fused-gate scratch (84 MB)
  // bf16 weights (fused QKV / KV; rest separate)
  bf16* WQKVf = (bf16*)carve((size_t)768*256*2);
  bf16* WQKVt = (bf16*)carve((size_t)768*256*2);
  bf16* WKVe  = (bf16*)carve((size_t)512*256*2);
  bf16* Wqeb  = (bf16*)carve((size_t)256*256*2);
  bf16* Wofb  = (bf16*)carve((size_t)256*256*2);
  bf16* Wotb  = (bf16*)carve((size_t)256*256*2);
  bf16* Woeb  = (bf16*)carve((size_t)256*256*2);
  bf16* W1b   = (bf16*)carve((size_t)HIDz*256*2);
  bf16* Wgb   = (bf16*)carve((size_t)HIDz*256*2);
  bf16* W2b   = (bf16*)carve((size_t)256*HIDz*2);

  const int DD = Dz*Dz;   // 65536
  {
    CvtArgs ca;
    const float* s12[12] = {Wqf,Wkf,Wvf, Wqt,Wkt,Wvt, Wke,Wve, Wqe,Wof,Wot,Woe};
    bf16* d12[12] = {WQKVf,WQKVf+DD,WQKVf+2*DD, WQKVt,WQKVt+DD,WQKVt+2*DD,
                     WKVe,WKVe+DD, Wqeb,Wofb,Wotb,Woeb};
    for (int i = 0; i < 12; ++i){ ca.src[i] = s12[i]; ca.dst[i] = d12[i]; }
    const float* sh[3] = {W1, Wg, W2};
    bf16* dh[3] = {W1b, Wgb, W2b};
    for (int j = 0; j < 3; ++j)
      for (int p = 0; p < 4; ++p){
        ca.src[12 + j*4 + p] = sh[j] + (size_t)p * DD;
        ca.dst[12 + j*4 + p] = dh[j] + (size_t)p * DD;
      }
    cvt_multi<<<dim3(DD/1024, 24), 256, 0, stream>>>(ca);
  }

  bf16* Qeb = QKVb + (size_t)TTR * 512;   // stage-C Q tile after KV rows

  // ---------------- Stage A: feature attention ----------------
  ln_kernel<<<TOK/4, 256, 0, stream>>>(x, Xn, gf, b2f, 0, 0);
  mgemm<0><<<3*(TOK/128), 512, 0, stream>>>(Xn, WQKVf, bqf, bkf, bvf, QKVb,
      nullptr, nullptr, TOK, 768, 256, 0,0, 3);
  attn_w<1,1><<<dim3(Bz*Sz, 2), 256, 0, stream>>>(QKVb, QKVb+256, QKVb+512, mask, Ob, 768, 768);
  mgemm<1><<<TOK/128, 512, 0, stream>>>(Ob, Wofb, bof, nullptr, nullptr, Y,
      x, nullptr, TOK, 256, 256, 0,0, 1);

  // ---------------- Stage B: train self-attention ----------------
  ln_kernel<<<TTR/4, 256, 0, stream>>>(Y, Xn, gt, b2t, NTRz, 0);
  mgemm<0><<<3*(TTR/128), 512, 0, stream>>>(Xn, WQKVt, bqt, bkt, bvt, QKVb,
      nullptr, nullptr, TTR, 768, 256, 0,0, 3);
  attn_t_m<<<dim3(NSEQ, 8), 256, 0, stream>>>(QKVb, QKVb+256, QKVb+512, Ob, 768);
  mgemm<1><<<TTR/128, 512, 0, stream>>>(Ob, Wotb, bot, nullptr, nullptr, Y,
      Y, nullptr, TTR, 256, 256, NTRz,0, 1);

  // ---------------- Stage C: cross attention ----------------
  ln_kernel<<<TTR/4, 256, 0, stream>>>(Y, Xn, ge, b2e, NTRz, 0);                      // kv rows
  ln_kernel<<<TTE/4, 256, 0, stream>>>(Y, Xn + (size_t)TTR*Dz, ge, b2e, NTEz, NTRz);  // query rows
  mgemm<0><<<TTE/128, 512, 0, stream>>>(Xn + (size_t)TTR*Dz, Wqeb, bqe,
      nullptr, nullptr, Qeb, nullptr, nullptr, TTE, 256, 256, 0,0, 1);
  mgemm<0><<<2*(TTR/128), 512, 0, stream>>>(Xn, WKVe, bke, bve, bve, QKVb,
      nullptr, nullptr, TTR, 512, 256, 0,0, 2);
  attn_w<4,0><<<dim3(NSEQ, 2), 256, 0, stream>>>(Qeb, QKVb, QKVb+256, nullptr, Ob, 256, 512);
  mgemm<1><<<TTE/128, 512, 0, stream>>>(Ob, Woeb, boe, nullptr, nullptr, Y,
      Y, nullptr, TTE, 256, 256, NTEz,NTRz, 1);

  // ---------------- Stage D: gated MLP (fused up-projection) ----------------
  ln_kernel<<<TOK/4, 256, 0, stream>>>(Y, Xn, gm, bm, 0, 0);
  for (int c = 0; c < TOK/CHD; ++c){
    const bf16* Anc = Xn + (size_t)c * CHD * Dz;
    float*      Yc  = Y  + (size_t)c * CHD * Dz;
    mgemm_dual<<<8*(CHD/128), 512, 0, stream>>>(Anc, W1b, Wgb, b1, bg,
        Hb, CHD, 256);
    mgemm<1><<<CHD/128, 512, 0, stream>>>(Hb, W2b, b2v, nullptr, nullptr,
        Yc, Yc, nullptr, CHD, 256, HIDz, 0,0, 1);
  }
}